// Round 1
// baseline (945.255 us; speedup 1.0000x reference)
//
#include <hip/hip_runtime.h>
#include <math.h>

#define HC 256      // H*C
#define NHEAD 4
#define NEG_SLOPE 0.2f
#define GG 64       // graphs

// ---------------- CSR build ----------------

__global__ void count_deg_kernel(const int* __restrict__ ei, int E, int Nn, int* __restrict__ deg) {
  int idx = blockIdx.x * 256 + threadIdx.x;
  int Et = E + Nn;
  if (idx >= Et) return;
  int d = (idx < E) ? ei[E + idx] : (idx - E);   // row1 of edge_index = dst; self loops appended
  atomicAdd(&deg[d], 1);
}

__global__ void scan_partial_kernel(const int* __restrict__ deg, int Nn,
                                    int* __restrict__ rowptr, int* __restrict__ bsum) {
  __shared__ int s[256];
  int t = threadIdx.x, i = blockIdx.x * 256 + t;
  int v = (i < Nn) ? deg[i] : 0;
  s[t] = v; __syncthreads();
  for (int off = 1; off < 256; off <<= 1) {
    int x = (t >= off) ? s[t - off] : 0; __syncthreads();
    s[t] += x; __syncthreads();
  }
  if (i < Nn) rowptr[i] = s[t] - v;          // exclusive within block
  if (t == 255) bsum[blockIdx.x] = s[t];     // block total
}

__global__ void scan_bsum_kernel(int* __restrict__ bsum, int nb) {
  __shared__ int s[512];
  int t = threadIdx.x;
  int v = (t < nb) ? bsum[t] : 0;
  s[t] = v; __syncthreads();
  for (int off = 1; off < 512; off <<= 1) {
    int x = (t >= off) ? s[t - off] : 0; __syncthreads();
    s[t] += x; __syncthreads();
  }
  if (t < nb) bsum[t] = s[t] - v;            // exclusive block offsets
}

__global__ void scan_add_kernel(int* __restrict__ rowptr, const int* __restrict__ bsum,
                                int Nn, int Etot) {
  int i = blockIdx.x * 256 + threadIdx.x;
  if (i < Nn) rowptr[i] += bsum[blockIdx.x];
  if (i == 0) rowptr[Nn] = Etot;
}

__global__ void fill_csr_kernel(const int* __restrict__ ei, int E, int Nn,
                                const int* __restrict__ rowptr, int* __restrict__ cursor,
                                int* __restrict__ col) {
  int idx = blockIdx.x * 256 + threadIdx.x;
  int Et = E + Nn;
  if (idx >= Et) return;
  int s, d;
  if (idx < E) { s = ei[idx]; d = ei[E + idx]; } else { s = d = idx - E; }
  int pos = atomicAdd(&cursor[d], 1);
  col[rowptr[d] + pos] = s;
}

// ---------------- layer 1 GEMM (K=2) ----------------

__global__ void gemm_k2_kernel(const float* __restrict__ x, const float* __restrict__ W,
                               float* __restrict__ h, int Nn) {
  int g = blockIdx.x * 256 + threadIdx.x;     // one thread per (node, 4-col group)
  int n = g >> 6, j = (g & 63) << 2;
  if (n >= Nn) return;
  float x0 = x[n * 2], x1 = x[n * 2 + 1];
  float4 w0 = *(const float4*)&W[j];
  float4 w1 = *(const float4*)&W[256 + j];
  float4 o;
  o.x = x0 * w0.x + x1 * w1.x;
  o.y = x0 * w0.y + x1 * w1.y;
  o.z = x0 * w0.z + x1 * w1.z;
  o.w = x0 * w0.w + x1 * w1.w;
  *(float4*)&h[(size_t)n * HC + j] = o;
}

// ---------------- fp32 tiled GEMM: [M,256] @ [256,256] ----------------

#define BM 64
#define BN 64
#define BK 32

__global__ __launch_bounds__(256) void gemm_f32_kernel(const float* __restrict__ A,
                                                       const float* __restrict__ B,
                                                       float* __restrict__ C, int Mrows) {
  __shared__ float As[BK][BM + 4];   // transposed A tile, padded (16B-aligned rows: 68*4=272)
  __shared__ float Bs[BK][BN];
  int bc = blockIdx.x, br = blockIdx.y;
  int tid = threadIdx.x;
  int tx = tid & 15, ty = tid >> 4;            // 16x16 threads, 4x4 microtile each
  int row0 = br * BM, col0 = bc * BN;
  float acc[4][4] = {};
  for (int k0 = 0; k0 < 256; k0 += BK) {
    #pragma unroll
    for (int l = 0; l < 2; ++l) {              // A: 64 rows x 32 cols
      int idx = tid + l * 256;
      int r = idx >> 3, c4 = (idx & 7) << 2;
      float4 v = make_float4(0.f, 0.f, 0.f, 0.f);
      int gr = row0 + r;
      if (gr < Mrows) v = *(const float4*)&A[(size_t)gr * 256 + k0 + c4];
      As[c4 + 0][r] = v.x; As[c4 + 1][r] = v.y; As[c4 + 2][r] = v.z; As[c4 + 3][r] = v.w;
    }
    #pragma unroll
    for (int l = 0; l < 2; ++l) {              // B: 32 rows x 64 cols
      int idx = tid + l * 256;
      int r = idx >> 4, c4 = (idx & 15) << 2;
      *(float4*)&Bs[r][c4] = *(const float4*)&B[(size_t)(k0 + r) * 256 + col0 + c4];
    }
    __syncthreads();
    #pragma unroll
    for (int kk = 0; kk < BK; ++kk) {
      float4 a = *(const float4*)&As[kk][ty * 4];
      float4 b = *(const float4*)&Bs[kk][tx * 4];
      acc[0][0] += a.x * b.x; acc[0][1] += a.x * b.y; acc[0][2] += a.x * b.z; acc[0][3] += a.x * b.w;
      acc[1][0] += a.y * b.x; acc[1][1] += a.y * b.y; acc[1][2] += a.y * b.z; acc[1][3] += a.y * b.w;
      acc[2][0] += a.z * b.x; acc[2][1] += a.z * b.y; acc[2][2] += a.z * b.z; acc[2][3] += a.z * b.w;
      acc[3][0] += a.w * b.x; acc[3][1] += a.w * b.y; acc[3][2] += a.w * b.z; acc[3][3] += a.w * b.w;
    }
    __syncthreads();
  }
  #pragma unroll
  for (int i = 0; i < 4; ++i) {
    int gr = row0 + ty * 4 + i;
    if (gr < Mrows) {
      float4 o = make_float4(acc[i][0], acc[i][1], acc[i][2], acc[i][3]);
      *(float4*)&C[(size_t)gr * 256 + col0 + tx * 4] = o;
    }
  }
}

// ---------------- attention logits ----------------

__global__ void attn_logits_kernel(const float* __restrict__ h, const float* __restrict__ as_,
                                   const float* __restrict__ ad_, float* __restrict__ als,
                                   float* __restrict__ ald, int Nn) {
  int wid = (blockIdx.x * blockDim.x + threadIdx.x) >> 6;
  int lane = threadIdx.x & 63;
  if (wid >= Nn) return;
  const float* hr = h + (size_t)wid * HC;
  float ps[4], pd[4];
  #pragma unroll
  for (int q = 0; q < 4; ++q) {
    float v = hr[q * 64 + lane];
    ps[q] = v * as_[q * 64 + lane];
    pd[q] = v * ad_[q * 64 + lane];
  }
  #pragma unroll
  for (int off = 32; off >= 1; off >>= 1) {
    #pragma unroll
    for (int q = 0; q < 4; ++q) {
      ps[q] += __shfl_xor(ps[q], off, 64);
      pd[q] += __shfl_xor(pd[q], off, 64);
    }
  }
  if (lane == 0) {
    *(float4*)&als[wid * 4] = make_float4(ps[0], ps[1], ps[2], ps[3]);
    *(float4*)&ald[wid * 4] = make_float4(pd[0], pd[1], pd[2], pd[3]);
  }
}

// ---------------- GAT gather: online softmax + weighted sum + bias + ELU ----------------

__global__ __launch_bounds__(256) void gat_gather_kernel(const float* __restrict__ h,
    const float* __restrict__ als, const float* __restrict__ ald,
    const int* __restrict__ rowptr, const int* __restrict__ col,
    const float* __restrict__ bias, float* __restrict__ out, int Nn) {
  int node = blockIdx.x * 4 + (threadIdx.x >> 6);
  int lane = threadIdx.x & 63;
  if (node >= Nn) return;
  float4 ad = *(const float4*)&ald[node * 4];
  float adv[4] = {ad.x, ad.y, ad.z, ad.w};
  float M[4], S[4], acc[4];
  #pragma unroll
  for (int q = 0; q < 4; ++q) { M[q] = -INFINITY; S[q] = 0.f; acc[q] = 0.f; }
  int rs = rowptr[node], re = rowptr[node + 1];
  for (int i = rs; i < re; ++i) {
    int s = col[i];
    float4 asv = *(const float4*)&als[s * 4];
    const float* hs = h + (size_t)s * HC;
    float ein[4] = {asv.x + adv[0], asv.y + adv[1], asv.z + adv[2], asv.w + adv[3]};
    #pragma unroll
    for (int q = 0; q < 4; ++q) {
      float ee = ein[q];
      ee = ee > 0.f ? ee : NEG_SLOPE * ee;
      float nm = fmaxf(M[q], ee);
      float sc = __expf(M[q] - nm);           // M=-inf on first edge -> 0
      float p  = __expf(ee - nm);
      float hv = hs[q * 64 + lane];
      S[q]   = S[q] * sc + p;
      acc[q] = acc[q] * sc + p * hv;
      M[q] = nm;
    }
  }
  float* orow = out + (size_t)node * HC;
  #pragma unroll
  for (int q = 0; q < 4; ++q) {
    float o = acc[q] / (S[q] + 1e-16f) + bias[q * 64 + lane];
    o = o > 0.f ? o : (__expf(o) - 1.0f);     // ELU (alpha=1)
    orow[q * 64 + lane] = o;
  }
}

// ---------------- pooling + MLP ----------------

__global__ void bounds_kernel(const int* __restrict__ batch, int Nn, int* __restrict__ bounds) {
  int g = threadIdx.x;
  if (g > GG) return;
  int lo = 0, hi = Nn;
  while (lo < hi) { int mid = (lo + hi) >> 1; if (batch[mid] < g) lo = mid + 1; else hi = mid; }
  bounds[g] = lo;   // lower_bound of g; bounds[64] = N
}

__global__ void pool_kernel(const float* __restrict__ X, const int* __restrict__ bounds,
                            float* __restrict__ pooled) {
  int g = blockIdx.x, split = blockIdx.y, t = threadIdx.x;
  int s = bounds[g], e = bounds[g + 1];
  int cnt = e - s;
  if (cnt <= 0) return;
  int chunk = (cnt + gridDim.y - 1) / gridDim.y;
  int s2 = s + split * chunk, e2 = min(e, s2 + chunk);
  if (s2 >= e2) return;
  float sum = 0.f;
  for (int n = s2; n < e2; ++n) sum += X[(size_t)n * HC + t];
  atomicAdd(&pooled[g * HC + t], sum);
}

__global__ __launch_bounds__(512) void mlp_kernel(const float* __restrict__ pooled,
    const int* __restrict__ bounds, const float* __restrict__ Wp1, const float* __restrict__ bp1,
    const float* __restrict__ Wp2, const float* __restrict__ bp2, float* __restrict__ out) {
  __shared__ float p[256];
  __shared__ float z1[512];
  int g = blockIdx.x, t = threadIdx.x;
  if (t < 256) {
    int cnt = bounds[g + 1] - bounds[g];
    float inv = 1.0f / (float)(cnt > 1 ? cnt : 1);
    p[t] = pooled[g * 256 + t] * inv;
  }
  __syncthreads();
  float a1 = bp1[t];
  for (int k = 0; k < 256; ++k) a1 += p[k] * Wp1[k * 512 + t];
  z1[t] = fmaxf(a1, 0.f);
  __syncthreads();
  if (t < 256) {
    float a2 = bp2[t];
    for (int k = 0; k < 512; ++k) a2 += z1[k] * Wp2[k * 256 + t];
    out[g * 256 + t] = a2;
  }
}

// ---------------- launch ----------------

static inline size_t align_up(size_t x, size_t a) { return (x + a - 1) & ~(a - 1); }

extern "C" void kernel_launch(void* const* d_in, const int* in_sizes, int n_in,
                              void* d_out, int out_size, void* d_ws, size_t ws_size,
                              hipStream_t stream) {
  const float* x    = (const float*)d_in[0];
  const int*   ei   = (const int*)d_in[1];
  const int*   batch= (const int*)d_in[2];
  const float* W1   = (const float*)d_in[3];
  const float* a1s  = (const float*)d_in[4];
  const float* a1d  = (const float*)d_in[5];
  const float* b1   = (const float*)d_in[6];
  const float* W2   = (const float*)d_in[7];
  const float* a2s  = (const float*)d_in[8];
  const float* a2d  = (const float*)d_in[9];
  const float* b2   = (const float*)d_in[10];
  const float* W3   = (const float*)d_in[11];
  const float* a3s  = (const float*)d_in[12];
  const float* a3d  = (const float*)d_in[13];
  const float* b3   = (const float*)d_in[14];
  const float* Wp1  = (const float*)d_in[15];
  const float* bp1  = (const float*)d_in[16];
  const float* Wp2  = (const float*)d_in[17];
  const float* bp2  = (const float*)d_in[18];

  const int N = in_sizes[0] / 2;       // 100000
  const int E = in_sizes[1] / 2;       // 400000
  const int Et = E + N;                // with self loops

  char* base = (char*)d_ws;
  size_t off = 0;
  auto alloc = [&](size_t bytes) { size_t o = off; off = align_up(off + bytes, 256); return o; };
  float* buf0   = (float*)(base + alloc((size_t)N * HC * 4));
  float* buf1   = (float*)(base + alloc((size_t)N * HC * 4));
  float* als    = (float*)(base + alloc((size_t)N * 4 * 4));
  float* ald    = (float*)(base + alloc((size_t)N * 4 * 4));
  int*   rowptr = (int*)  (base + alloc((size_t)(N + 1) * 4));
  int*   col    = (int*)  (base + alloc((size_t)Et * 4));
  int*   deg    = (int*)  (base + alloc((size_t)N * 4));
  int*   cursor = (int*)  (base + alloc((size_t)N * 4));
  int*   bsum   = (int*)  (base + alloc(512 * 4));
  int*   bounds = (int*)  (base + alloc((GG + 1) * 4));
  float* pooled = (float*)(base + alloc((size_t)GG * HC * 4));
  (void)ws_size; (void)n_in; (void)out_size;

  hipMemsetAsync(deg, 0, (size_t)N * 4, stream);
  hipMemsetAsync(cursor, 0, (size_t)N * 4, stream);
  hipMemsetAsync(pooled, 0, (size_t)GG * HC * 4, stream);

  // CSR by destination (same edge set for all layers)
  int ebk = (Et + 255) / 256;
  count_deg_kernel<<<ebk, 256, 0, stream>>>(ei, E, N, deg);
  int NT = (N + 255) / 256;
  scan_partial_kernel<<<NT, 256, 0, stream>>>(deg, N, rowptr, bsum);
  scan_bsum_kernel<<<1, 512, 0, stream>>>(bsum, NT);
  scan_add_kernel<<<NT, 256, 0, stream>>>(rowptr, bsum, N, Et);
  fill_csr_kernel<<<ebk, 256, 0, stream>>>(ei, E, N, rowptr, cursor, col);

  dim3 gemm_grid(HC / BN, (N + BM - 1) / BM);
  int nodeblk = (N + 3) / 4;

  // layer 1 (in=2)
  gemm_k2_kernel<<<(N * 64 + 255) / 256, 256, 0, stream>>>(x, W1, buf0, N);
  attn_logits_kernel<<<nodeblk, 256, 0, stream>>>(buf0, a1s, a1d, als, ald, N);
  gat_gather_kernel<<<nodeblk, 256, 0, stream>>>(buf0, als, ald, rowptr, col, b1, buf1, N);

  // layer 2
  gemm_f32_kernel<<<gemm_grid, 256, 0, stream>>>(buf1, W2, buf0, N);
  attn_logits_kernel<<<nodeblk, 256, 0, stream>>>(buf0, a2s, a2d, als, ald, N);
  gat_gather_kernel<<<nodeblk, 256, 0, stream>>>(buf0, als, ald, rowptr, col, b2, buf1, N);

  // layer 3
  gemm_f32_kernel<<<gemm_grid, 256, 0, stream>>>(buf1, W3, buf0, N);
  attn_logits_kernel<<<nodeblk, 256, 0, stream>>>(buf0, a3s, a3d, als, ald, N);
  gat_gather_kernel<<<nodeblk, 256, 0, stream>>>(buf0, als, ald, rowptr, col, b3, buf1, N);

  // pool + MLP
  bounds_kernel<<<1, 128, 0, stream>>>(batch, N, bounds);
  pool_kernel<<<dim3(GG, 8), 256, 0, stream>>>(buf1, bounds, pooled);
  mlp_kernel<<<GG, 512, 0, stream>>>(pooled, bounds, Wp1, bp1, Wp2, bp2, (float*)d_out);
}

// Round 2
// 735.904 us; speedup vs baseline: 1.2845x; 1.2845x over previous
//
#include <hip/hip_runtime.h>
#include <math.h>

#define HC 256      // H*C
#define NHEAD 4
#define NEG_SLOPE 0.2f
#define GG 64       // graphs

typedef unsigned short u16;
typedef unsigned int u32;
typedef __attribute__((ext_vector_type(8))) short short8;
typedef __attribute__((ext_vector_type(4))) float f32x4;

static __device__ inline u16 f2bf_rn(float f) {
  u32 x = __float_as_uint(f);
  u32 r = (x + 0x7fffu + ((x >> 16) & 1u)) >> 16;
  return (u16)r;
}
static __device__ inline float bf2f(u16 u) { return __uint_as_float(((u32)u) << 16); }

// ---------------- CSR build ----------------

__global__ void count_deg_kernel(const int* __restrict__ ei, int E, int Nn, int* __restrict__ deg) {
  int idx = blockIdx.x * 256 + threadIdx.x;
  int Et = E + Nn;
  if (idx >= Et) return;
  int d = (idx < E) ? ei[E + idx] : (idx - E);   // row1 of edge_index = dst; self loops appended
  atomicAdd(&deg[d], 1);
}

__global__ void scan_partial_kernel(const int* __restrict__ deg, int Nn,
                                    int* __restrict__ rowptr, int* __restrict__ bsum) {
  __shared__ int s[256];
  int t = threadIdx.x, i = blockIdx.x * 256 + t;
  int v = (i < Nn) ? deg[i] : 0;
  s[t] = v; __syncthreads();
  for (int off = 1; off < 256; off <<= 1) {
    int x = (t >= off) ? s[t - off] : 0; __syncthreads();
    s[t] += x; __syncthreads();
  }
  if (i < Nn) rowptr[i] = s[t] - v;          // exclusive within block
  if (t == 255) bsum[blockIdx.x] = s[t];     // block total
}

__global__ void scan_bsum_kernel(int* __restrict__ bsum, int nb) {
  __shared__ int s[512];
  int t = threadIdx.x;
  int v = (t < nb) ? bsum[t] : 0;
  s[t] = v; __syncthreads();
  for (int off = 1; off < 512; off <<= 1) {
    int x = (t >= off) ? s[t - off] : 0; __syncthreads();
    s[t] += x; __syncthreads();
  }
  if (t < nb) bsum[t] = s[t] - v;            // exclusive block offsets
}

__global__ void scan_add_kernel(int* __restrict__ rowptr, const int* __restrict__ bsum,
                                int Nn, int Etot) {
  int i = blockIdx.x * 256 + threadIdx.x;
  if (i < Nn) rowptr[i] += bsum[blockIdx.x];
  if (i == 0) rowptr[Nn] = Etot;
}

__global__ void fill_csr_kernel(const int* __restrict__ ei, int E, int Nn,
                                const int* __restrict__ rowptr, int* __restrict__ cursor,
                                int* __restrict__ col) {
  int idx = blockIdx.x * 256 + threadIdx.x;
  int Et = E + Nn;
  if (idx >= Et) return;
  int s, d;
  if (idx < E) { s = ei[idx]; d = ei[E + idx]; } else { s = d = idx - E; }
  int pos = atomicAdd(&cursor[d], 1);
  col[rowptr[d] + pos] = s;
}

// ---------------- W transpose + hi/lo bf16 split: Wt[n][k] ----------------

__global__ void convert_w_kernel(const float* __restrict__ W, u16* __restrict__ hi,
                                 u16* __restrict__ lo) {
  int idx = blockIdx.x * 256 + threadIdx.x;    // 65536 threads
  if (idx >= 256 * 256) return;
  int k = idx >> 8, n = idx & 255;             // coalesced read of W[k][n]
  float v = W[idx];
  u16 h = f2bf_rn(v);
  u16 l = f2bf_rn(v - bf2f(h));
  hi[n * 256 + k] = h;
  lo[n * 256 + k] = l;
}

// ---------------- layer 1 GEMM (K=2) ----------------

__global__ void gemm_k2_kernel(const float* __restrict__ x, const float* __restrict__ W,
                               float* __restrict__ h, int Nn) {
  int g = blockIdx.x * 256 + threadIdx.x;     // one thread per (node, 4-col group)
  int n = g >> 6, j = (g & 63) << 2;
  if (n >= Nn) return;
  float x0 = x[n * 2], x1 = x[n * 2 + 1];
  float4 w0 = *(const float4*)&W[j];
  float4 w1 = *(const float4*)&W[256 + j];
  float4 o;
  o.x = x0 * w0.x + x1 * w1.x;
  o.y = x0 * w0.y + x1 * w1.y;
  o.z = x0 * w0.z + x1 * w1.z;
  o.w = x0 * w0.w + x1 * w1.w;
  *(float4*)&h[(size_t)n * HC + j] = o;
}

// ---------------- split-bf16 MFMA GEMM: [M,256] @ [256,256] -> fp32 ----------------
// A given as hi/lo bf16 [M][256]; B given as transposed hi/lo bf16 Wt[n][k].
// C = Ahi@Bhi + Ahi@Blo + Alo@Bhi (lo*lo dropped; rel err ~2^-16).

#define GBM 128
#define GBN 128
#define GBK 32
#define LSTR 40   // padded LDS row stride (shorts); 80 B = 5*16 -> 16B-aligned rows

__global__ __launch_bounds__(256) void gemm_mfma_kernel(
    const u16* __restrict__ Ahi, const u16* __restrict__ Alo,
    const u16* __restrict__ Bhi, const u16* __restrict__ Blo,
    float* __restrict__ C, int Mrows) {
  __shared__ __align__(16) u16 As[2][GBM][LSTR];
  __shared__ __align__(16) u16 Bs[2][GBN][LSTR];
  int bc = blockIdx.x, br = blockIdx.y;
  int tid = threadIdx.x;
  int wid = tid >> 6, lane = tid & 63;
  int wr = wid >> 1, wc = wid & 1;             // 2x2 wave grid, 64x64 per wave
  int row0 = br * GBM, col0 = bc * GBN;
  int fr = lane & 15, fg = lane >> 4;

  f32x4 acc[4][4];
  #pragma unroll
  for (int m = 0; m < 4; ++m)
    #pragma unroll
    for (int n = 0; n < 4; ++n) acc[m][n] = (f32x4){0.f, 0.f, 0.f, 0.f};

  for (int k0 = 0; k0 < 256; k0 += GBK) {
    // stage A(128x32) and B(128x32) hi+lo; unit = 8 bf16 (16 B)
    #pragma unroll
    for (int l = 0; l < 2; ++l) {
      int u = tid + l * 256;                   // 0..511
      int r = u >> 2, kc = (u & 3) << 3;       // row, k-chunk*8
      int gr = row0 + r; if (gr >= Mrows) gr = Mrows - 1;
      size_t ga = (size_t)gr * 256 + k0 + kc;
      *(uint4*)&As[0][r][kc] = *(const uint4*)&Ahi[ga];
      *(uint4*)&As[1][r][kc] = *(const uint4*)&Alo[ga];
      size_t gb = (size_t)(col0 + r) * 256 + k0 + kc;
      *(uint4*)&Bs[0][r][kc] = *(const uint4*)&Bhi[gb];
      *(uint4*)&Bs[1][r][kc] = *(const uint4*)&Blo[gb];
    }
    __syncthreads();

    short8 ah[4], al[4], bh[4], bl[4];
    #pragma unroll
    for (int m = 0; m < 4; ++m) {
      int r = wr * 64 + m * 16 + fr;
      ah[m] = *(const short8*)&As[0][r][fg * 8];
      al[m] = *(const short8*)&As[1][r][fg * 8];
    }
    #pragma unroll
    for (int n = 0; n < 4; ++n) {
      int c = wc * 64 + n * 16 + fr;
      bh[n] = *(const short8*)&Bs[0][c][fg * 8];
      bl[n] = *(const short8*)&Bs[1][c][fg * 8];
    }
    #pragma unroll
    for (int m = 0; m < 4; ++m)
      #pragma unroll
      for (int n = 0; n < 4; ++n) {
        acc[m][n] = __builtin_amdgcn_mfma_f32_16x16x32_bf16(ah[m], bh[n], acc[m][n], 0, 0, 0);
        acc[m][n] = __builtin_amdgcn_mfma_f32_16x16x32_bf16(ah[m], bl[n], acc[m][n], 0, 0, 0);
        acc[m][n] = __builtin_amdgcn_mfma_f32_16x16x32_bf16(al[m], bh[n], acc[m][n], 0, 0, 0);
      }
    __syncthreads();
  }

  // epilogue: C[row][col], col=lane&15 within 16x16 frag, row=(lane>>4)*4+j
  #pragma unroll
  for (int m = 0; m < 4; ++m) {
    #pragma unroll
    for (int n = 0; n < 4; ++n) {
      int col = col0 + wc * 64 + n * 16 + fr;
      #pragma unroll
      for (int j = 0; j < 4; ++j) {
        int row = row0 + wr * 64 + m * 16 + fg * 4 + j;
        if (row < Mrows) C[(size_t)row * 256 + col] = acc[m][n][j];
      }
    }
  }
}

// ---------------- attention logits ----------------

__global__ void attn_logits_kernel(const float* __restrict__ h, const float* __restrict__ as_,
                                   const float* __restrict__ ad_, float* __restrict__ als,
                                   float* __restrict__ ald, int Nn) {
  int wid = (blockIdx.x * blockDim.x + threadIdx.x) >> 6;
  int lane = threadIdx.x & 63;
  if (wid >= Nn) return;
  const float* hr = h + (size_t)wid * HC;
  float ps[4], pd[4];
  #pragma unroll
  for (int q = 0; q < 4; ++q) {
    float v = hr[q * 64 + lane];
    ps[q] = v * as_[q * 64 + lane];
    pd[q] = v * ad_[q * 64 + lane];
  }
  #pragma unroll
  for (int off = 32; off >= 1; off >>= 1) {
    #pragma unroll
    for (int q = 0; q < 4; ++q) {
      ps[q] += __shfl_xor(ps[q], off, 64);
      pd[q] += __shfl_xor(pd[q], off, 64);
    }
  }
  if (lane == 0) {
    *(float4*)&als[wid * 4] = make_float4(ps[0], ps[1], ps[2], ps[3]);
    *(float4*)&ald[wid * 4] = make_float4(pd[0], pd[1], pd[2], pd[3]);
  }
}

// ---------------- GAT gather: online softmax + weighted sum + bias + ELU ----------------
// MODE 0: write fp32. MODE 1: write bf16 hi/lo split pair (next GEMM's A operand).

template <int MODE>
__global__ __launch_bounds__(256) void gat_gather_kernel(const float* __restrict__ h,
    const float* __restrict__ als, const float* __restrict__ ald,
    const int* __restrict__ rowptr, const int* __restrict__ col,
    const float* __restrict__ bias, float* __restrict__ outf,
    u16* __restrict__ outhi, u16* __restrict__ outlo, int Nn) {
  int node = blockIdx.x * 4 + (threadIdx.x >> 6);
  int lane = threadIdx.x & 63;
  if (node >= Nn) return;
  float4 ad = *(const float4*)&ald[node * 4];
  float adv[4] = {ad.x, ad.y, ad.z, ad.w};
  float M[4], S[4], acc[4];
  #pragma unroll
  for (int q = 0; q < 4; ++q) { M[q] = -INFINITY; S[q] = 0.f; acc[q] = 0.f; }
  int rs = rowptr[node], re = rowptr[node + 1];
  for (int i = rs; i < re; ++i) {
    int s = col[i];
    float4 asv = *(const float4*)&als[s * 4];
    const float* hs = h + (size_t)s * HC;
    float ein[4] = {asv.x + adv[0], asv.y + adv[1], asv.z + adv[2], asv.w + adv[3]};
    #pragma unroll
    for (int q = 0; q < 4; ++q) {
      float ee = ein[q];
      ee = ee > 0.f ? ee : NEG_SLOPE * ee;
      float nm = fmaxf(M[q], ee);
      float sc = __expf(M[q] - nm);           // M=-inf on first edge -> 0
      float p  = __expf(ee - nm);
      float hv = hs[q * 64 + lane];
      S[q]   = S[q] * sc + p;
      acc[q] = acc[q] * sc + p * hv;
      M[q] = nm;
    }
  }
  #pragma unroll
  for (int q = 0; q < 4; ++q) {
    float o = acc[q] / (S[q] + 1e-16f) + bias[q * 64 + lane];
    o = o > 0.f ? o : (__expf(o) - 1.0f);     // ELU (alpha=1)
    size_t idx = (size_t)node * HC + q * 64 + lane;
    if (MODE == 0) {
      outf[idx] = o;
    } else {
      u16 hb = f2bf_rn(o);
      u16 lb = f2bf_rn(o - bf2f(hb));
      outhi[idx] = hb;
      outlo[idx] = lb;
    }
  }
}

// ---------------- pooling + MLP ----------------

__global__ void bounds_kernel(const int* __restrict__ batch, int Nn, int* __restrict__ bounds) {
  int g = threadIdx.x;
  if (g > GG) return;
  int lo = 0, hi = Nn;
  while (lo < hi) { int mid = (lo + hi) >> 1; if (batch[mid] < g) lo = mid + 1; else hi = mid; }
  bounds[g] = lo;   // lower_bound of g; bounds[64] = N
}

__global__ void pool_kernel(const float* __restrict__ X, const int* __restrict__ bounds,
                            float* __restrict__ pooled) {
  int g = blockIdx.x, split = blockIdx.y, t = threadIdx.x;
  int s = bounds[g], e = bounds[g + 1];
  int cnt = e - s;
  if (cnt <= 0) return;
  int chunk = (cnt + gridDim.y - 1) / gridDim.y;
  int s2 = s + split * chunk, e2 = min(e, s2 + chunk);
  if (s2 >= e2) return;
  float sum = 0.f;
  for (int n = s2; n < e2; ++n) sum += X[(size_t)n * HC + t];
  atomicAdd(&pooled[g * HC + t], sum);
}

__global__ __launch_bounds__(512) void mlp_kernel(const float* __restrict__ pooled,
    const int* __restrict__ bounds, const float* __restrict__ Wp1, const float* __restrict__ bp1,
    const float* __restrict__ Wp2, const float* __restrict__ bp2, float* __restrict__ out) {
  __shared__ float p[256];
  __shared__ float z1[512];
  int g = blockIdx.x, t = threadIdx.x;
  if (t < 256) {
    int cnt = bounds[g + 1] - bounds[g];
    float inv = 1.0f / (float)(cnt > 1 ? cnt : 1);
    p[t] = pooled[g * 256 + t] * inv;
  }
  __syncthreads();
  float a1 = bp1[t];
  for (int k = 0; k < 256; ++k) a1 += p[k] * Wp1[k * 512 + t];
  z1[t] = fmaxf(a1, 0.f);
  __syncthreads();
  if (t < 256) {
    float a2 = bp2[t];
    for (int k = 0; k < 512; ++k) a2 += z1[k] * Wp2[k * 256 + t];
    out[g * 256 + t] = a2;
  }
}

// ---------------- launch ----------------

static inline size_t align_up(size_t x, size_t a) { return (x + a - 1) & ~(a - 1); }

extern "C" void kernel_launch(void* const* d_in, const int* in_sizes, int n_in,
                              void* d_out, int out_size, void* d_ws, size_t ws_size,
                              hipStream_t stream) {
  const float* x    = (const float*)d_in[0];
  const int*   ei   = (const int*)d_in[1];
  const int*   batch= (const int*)d_in[2];
  const float* W1   = (const float*)d_in[3];
  const float* a1s  = (const float*)d_in[4];
  const float* a1d  = (const float*)d_in[5];
  const float* b1   = (const float*)d_in[6];
  const float* W2   = (const float*)d_in[7];
  const float* a2s  = (const float*)d_in[8];
  const float* a2d  = (const float*)d_in[9];
  const float* b2   = (const float*)d_in[10];
  const float* W3   = (const float*)d_in[11];
  const float* a3s  = (const float*)d_in[12];
  const float* a3d  = (const float*)d_in[13];
  const float* b3   = (const float*)d_in[14];
  const float* Wp1  = (const float*)d_in[15];
  const float* bp1  = (const float*)d_in[16];
  const float* Wp2  = (const float*)d_in[17];
  const float* bp2  = (const float*)d_in[18];

  const int N = in_sizes[0] / 2;       // 100000
  const int E = in_sizes[1] / 2;       // 400000
  const int Et = E + N;                // with self loops

  char* base = (char*)d_ws;
  size_t off = 0;
  auto alloc = [&](size_t bytes) { size_t o = off; off = align_up(off + bytes, 256); return o; };
  float* buf0   = (float*)(base + alloc((size_t)N * HC * 4));
  float* buf1   = (float*)(base + alloc((size_t)N * HC * 4));   // doubles as bf16 hi/lo pair
  float* als    = (float*)(base + alloc((size_t)N * 4 * 4));
  float* ald    = (float*)(base + alloc((size_t)N * 4 * 4));
  int*   rowptr = (int*)  (base + alloc((size_t)(N + 1) * 4));
  int*   col    = (int*)  (base + alloc((size_t)Et * 4));
  int*   deg    = (int*)  (base + alloc((size_t)N * 4));
  int*   cursor = (int*)  (base + alloc((size_t)N * 4));
  int*   bsum   = (int*)  (base + alloc(512 * 4));
  int*   bounds = (int*)  (base + alloc((GG + 1) * 4));
  float* pooled = (float*)(base + alloc((size_t)GG * HC * 4));
  (void)ws_size; (void)n_in; (void)out_size;

  // bf16 hi/lo views: x-pair in buf1's footprint (same bytes: 2*2B vs 4B)
  u16* xhi = (u16*)buf1;
  u16* xlo = xhi + (size_t)N * HC;
  // W2t/W3t hi/lo parked in deg/cursor space (dead after CSR build; 400 KB >= 256 KB)
  u16* W2thi = (u16*)deg;    u16* W2tlo = W2thi + 256 * 256;
  u16* W3thi = (u16*)cursor; u16* W3tlo = W3thi + 256 * 256;

  hipMemsetAsync(deg, 0, (size_t)N * 4, stream);
  hipMemsetAsync(cursor, 0, (size_t)N * 4, stream);
  hipMemsetAsync(pooled, 0, (size_t)GG * HC * 4, stream);

  // CSR by destination (same edge set for all layers)
  int ebk = (Et + 255) / 256;
  count_deg_kernel<<<ebk, 256, 0, stream>>>(ei, E, N, deg);
  int NT = (N + 255) / 256;
  scan_partial_kernel<<<NT, 256, 0, stream>>>(deg, N, rowptr, bsum);
  scan_bsum_kernel<<<1, 512, 0, stream>>>(bsum, NT);
  scan_add_kernel<<<NT, 256, 0, stream>>>(rowptr, bsum, N, Et);
  fill_csr_kernel<<<ebk, 256, 0, stream>>>(ei, E, N, rowptr, cursor, col);

  // weight conversion (deg/cursor now dead)
  convert_w_kernel<<<256, 256, 0, stream>>>(W2, W2thi, W2tlo);
  convert_w_kernel<<<256, 256, 0, stream>>>(W3, W3thi, W3tlo);

  dim3 gemm_grid(HC / GBN, (N + GBM - 1) / GBM);
  int nodeblk = (N + 3) / 4;

  // layer 1 (in=2)
  gemm_k2_kernel<<<(N * 64 + 255) / 256, 256, 0, stream>>>(x, W1, buf0, N);
  attn_logits_kernel<<<nodeblk, 256, 0, stream>>>(buf0, a1s, a1d, als, ald, N);
  gat_gather_kernel<1><<<nodeblk, 256, 0, stream>>>(buf0, als, ald, rowptr, col, b1,
                                                    nullptr, xhi, xlo, N);
  // layer 2
  gemm_mfma_kernel<<<gemm_grid, 256, 0, stream>>>(xhi, xlo, W2thi, W2tlo, buf0, N);
  attn_logits_kernel<<<nodeblk, 256, 0, stream>>>(buf0, a2s, a2d, als, ald, N);
  gat_gather_kernel<1><<<nodeblk, 256, 0, stream>>>(buf0, als, ald, rowptr, col, b2,
                                                    nullptr, xhi, xlo, N);
  // layer 3
  gemm_mfma_kernel<<<gemm_grid, 256, 0, stream>>>(xhi, xlo, W3thi, W3tlo, buf0, N);
  attn_logits_kernel<<<nodeblk, 256, 0, stream>>>(buf0, a3s, a3d, als, ald, N);
  gat_gather_kernel<0><<<nodeblk, 256, 0, stream>>>(buf0, als, ald, rowptr, col, b3,
                                                    buf1, nullptr, nullptr, N);

  // pool + MLP
  bounds_kernel<<<1, 128, 0, stream>>>(batch, N, bounds);
  pool_kernel<<<dim3(GG, 8), 256, 0, stream>>>(buf1, bounds, pooled);
  mlp_kernel<<<GG, 512, 0, stream>>>(pooled, bounds, Wp1, bp1, Wp2, bp2, (float*)d_out);
}

// Round 3
// 658.554 us; speedup vs baseline: 1.4353x; 1.1175x over previous
//
#include <hip/hip_runtime.h>
#include <math.h>

#define HC 256      // H*C
#define NHEAD 4
#define NEG_SLOPE 0.2f
#define GG 64       // graphs

typedef unsigned short u16;
typedef unsigned int u32;
typedef __attribute__((ext_vector_type(8))) short short8;
typedef __attribute__((ext_vector_type(4))) float f32x4;

static __device__ inline u16 f2bf_rn(float f) {
  u32 x = __float_as_uint(f);
  u32 r = (x + 0x7fffu + ((x >> 16) & 1u)) >> 16;
  return (u16)r;
}
static __device__ inline float bf2f(u16 u) { return __uint_as_float(((u32)u) << 16); }

// ---------------- CSR build ----------------

__global__ void count_deg_kernel(const int* __restrict__ ei, int E, int Nn, int* __restrict__ deg) {
  int idx = blockIdx.x * 256 + threadIdx.x;
  int Et = E + Nn;
  if (idx >= Et) return;
  int d = (idx < E) ? ei[E + idx] : (idx - E);   // row1 of edge_index = dst; self loops appended
  atomicAdd(&deg[d], 1);
}

__global__ void scan_partial_kernel(const int* __restrict__ deg, int Nn,
                                    int* __restrict__ rowptr, int* __restrict__ bsum) {
  __shared__ int s[256];
  int t = threadIdx.x, i = blockIdx.x * 256 + t;
  int v = (i < Nn) ? deg[i] : 0;
  s[t] = v; __syncthreads();
  for (int off = 1; off < 256; off <<= 1) {
    int x = (t >= off) ? s[t - off] : 0; __syncthreads();
    s[t] += x; __syncthreads();
  }
  if (i < Nn) rowptr[i] = s[t] - v;          // exclusive within block
  if (t == 255) bsum[blockIdx.x] = s[t];     // block total
}

__global__ void scan_bsum_kernel(int* __restrict__ bsum, int nb) {
  __shared__ int s[512];
  int t = threadIdx.x;
  int v = (t < nb) ? bsum[t] : 0;
  s[t] = v; __syncthreads();
  for (int off = 1; off < 512; off <<= 1) {
    int x = (t >= off) ? s[t - off] : 0; __syncthreads();
    s[t] += x; __syncthreads();
  }
  if (t < nb) bsum[t] = s[t] - v;            // exclusive block offsets
}

__global__ void scan_add_kernel(int* __restrict__ rowptr, const int* __restrict__ bsum,
                                int Nn, int Etot) {
  int i = blockIdx.x * 256 + threadIdx.x;
  if (i < Nn) rowptr[i] += bsum[blockIdx.x];
  if (i == 0) rowptr[Nn] = Etot;
}

__global__ void fill_csr_kernel(const int* __restrict__ ei, int E, int Nn,
                                const int* __restrict__ rowptr, int* __restrict__ cursor,
                                int* __restrict__ col) {
  int idx = blockIdx.x * 256 + threadIdx.x;
  int Et = E + Nn;
  if (idx >= Et) return;
  int s, d;
  if (idx < E) { s = ei[idx]; d = ei[E + idx]; } else { s = d = idx - E; }
  int pos = atomicAdd(&cursor[d], 1);
  col[rowptr[d] + pos] = s;
}

// ---------------- W transpose + hi/lo bf16 split: Wt[n][k] ----------------

__global__ void convert_w_kernel(const float* __restrict__ W, u16* __restrict__ hi,
                                 u16* __restrict__ lo) {
  int idx = blockIdx.x * 256 + threadIdx.x;    // 65536 threads
  if (idx >= 256 * 256) return;
  int k = idx >> 8, n = idx & 255;             // coalesced read of W[k][n]
  float v = W[idx];
  u16 h = f2bf_rn(v);
  u16 l = f2bf_rn(v - bf2f(h));
  hi[n * 256 + k] = h;
  lo[n * 256 + k] = l;
}

// ---------------- layer 1: K=2 GEMM fused with attention logits ----------------
// wave per node; lane handles cols {lane, lane+64, lane+128, lane+192} (one per head)

__global__ __launch_bounds__(256) void gemm_k2_logits_kernel(
    const float* __restrict__ x, const float* __restrict__ W,
    const float* __restrict__ as_, const float* __restrict__ ad_,
    float* __restrict__ h, float* __restrict__ als, float* __restrict__ ald, int Nn) {
  int node = blockIdx.x * 4 + (threadIdx.x >> 6);
  int lane = threadIdx.x & 63;
  if (node >= Nn) return;
  float x0 = x[node * 2], x1 = x[node * 2 + 1];
  float ps[4], pd[4];
  #pragma unroll
  for (int q = 0; q < 4; ++q) {
    int c = q * 64 + lane;
    float o = x0 * W[c] + x1 * W[256 + c];
    h[(size_t)node * HC + c] = o;
    ps[q] = o * as_[c];
    pd[q] = o * ad_[c];
  }
  #pragma unroll
  for (int off = 32; off >= 1; off >>= 1) {
    #pragma unroll
    for (int q = 0; q < 4; ++q) {
      ps[q] += __shfl_xor(ps[q], off, 64);
      pd[q] += __shfl_xor(pd[q], off, 64);
    }
  }
  if (lane == 0) {
    *(float4*)&als[node * 4] = make_float4(ps[0], ps[1], ps[2], ps[3]);
    *(float4*)&ald[node * 4] = make_float4(pd[0], pd[1], pd[2], pd[3]);
  }
}

// ---------------- split-bf16 MFMA GEMM + fused attention logits ----------------
// A as hi/lo bf16 [M][256]; B transposed hi/lo bf16 Wt[n][k].
// C = Ahi@Bhi + Ahi@Blo + Alo@Bhi. Epilogue also emits als/ald (each wave's
// 64-col range is exactly one head: head = bc*2 + wc).

#define GBM 128
#define GBN 128
#define GBK 32
#define LSTR 40   // padded LDS row stride (shorts); 80 B = 5*16 -> 16B-aligned rows

__global__ __launch_bounds__(256) void gemm_mfma_kernel(
    const u16* __restrict__ Ahi, const u16* __restrict__ Alo,
    const u16* __restrict__ Bhi, const u16* __restrict__ Blo,
    const float* __restrict__ as_, const float* __restrict__ ad_,
    float* __restrict__ C, float* __restrict__ als, float* __restrict__ ald, int Mrows) {
  __shared__ __align__(16) u16 As[2][GBM][LSTR];
  __shared__ __align__(16) u16 Bs[2][GBN][LSTR];
  int bc = blockIdx.x, br = blockIdx.y;
  int tid = threadIdx.x;
  int wid = tid >> 6, lane = tid & 63;
  int wr = wid >> 1, wc = wid & 1;             // 2x2 wave grid, 64x64 per wave
  int row0 = br * GBM, col0 = bc * GBN;
  int fr = lane & 15, fg = lane >> 4;

  f32x4 acc[4][4];
  #pragma unroll
  for (int m = 0; m < 4; ++m)
    #pragma unroll
    for (int n = 0; n < 4; ++n) acc[m][n] = (f32x4){0.f, 0.f, 0.f, 0.f};

  for (int k0 = 0; k0 < 256; k0 += GBK) {
    #pragma unroll
    for (int l = 0; l < 2; ++l) {
      int u = tid + l * 256;                   // 0..511
      int r = u >> 2, kc = (u & 3) << 3;       // row, k-chunk*8
      int gr = row0 + r; if (gr >= Mrows) gr = Mrows - 1;
      size_t ga = (size_t)gr * 256 + k0 + kc;
      *(uint4*)&As[0][r][kc] = *(const uint4*)&Ahi[ga];
      *(uint4*)&As[1][r][kc] = *(const uint4*)&Alo[ga];
      size_t gb = (size_t)(col0 + r) * 256 + k0 + kc;
      *(uint4*)&Bs[0][r][kc] = *(const uint4*)&Bhi[gb];
      *(uint4*)&Bs[1][r][kc] = *(const uint4*)&Blo[gb];
    }
    __syncthreads();

    short8 ah[4], al[4], bh[4], bl[4];
    #pragma unroll
    for (int m = 0; m < 4; ++m) {
      int r = wr * 64 + m * 16 + fr;
      ah[m] = *(const short8*)&As[0][r][fg * 8];
      al[m] = *(const short8*)&As[1][r][fg * 8];
    }
    #pragma unroll
    for (int n = 0; n < 4; ++n) {
      int c = wc * 64 + n * 16 + fr;
      bh[n] = *(const short8*)&Bs[0][c][fg * 8];
      bl[n] = *(const short8*)&Bs[1][c][fg * 8];
    }
    #pragma unroll
    for (int m = 0; m < 4; ++m)
      #pragma unroll
      for (int n = 0; n < 4; ++n) {
        acc[m][n] = __builtin_amdgcn_mfma_f32_16x16x32_bf16(ah[m], bh[n], acc[m][n], 0, 0, 0);
        acc[m][n] = __builtin_amdgcn_mfma_f32_16x16x32_bf16(ah[m], bl[n], acc[m][n], 0, 0, 0);
        acc[m][n] = __builtin_amdgcn_mfma_f32_16x16x32_bf16(al[m], bh[n], acc[m][n], 0, 0, 0);
      }
    __syncthreads();
  }

  // C write: col=lane&15 within frag, row=(lane>>4)*4+j
  #pragma unroll
  for (int m = 0; m < 4; ++m) {
    #pragma unroll
    for (int n = 0; n < 4; ++n) {
      int col = col0 + wc * 64 + n * 16 + fr;
      #pragma unroll
      for (int j = 0; j < 4; ++j) {
        int row = row0 + wr * 64 + m * 16 + fg * 4 + j;
        if (row < Mrows) C[(size_t)row * 256 + col] = acc[m][n][j];
      }
    }
  }

  // fused logits: this wave's cols = one head
  int head = bc * 2 + wc;
  float asv[4], adv[4];
  #pragma unroll
  for (int n = 0; n < 4; ++n) {
    asv[n] = as_[head * 64 + n * 16 + fr];
    adv[n] = ad_[head * 64 + n * 16 + fr];
  }
  #pragma unroll
  for (int m = 0; m < 4; ++m) {
    #pragma unroll
    for (int j = 0; j < 4; ++j) {
      float ps = 0.f, pd = 0.f;
      #pragma unroll
      for (int n = 0; n < 4; ++n) {
        ps += acc[m][n][j] * asv[n];
        pd += acc[m][n][j] * adv[n];
      }
      #pragma unroll
      for (int off = 1; off < 16; off <<= 1) {
        ps += __shfl_xor(ps, off, 64);
        pd += __shfl_xor(pd, off, 64);
      }
      int grow = row0 + wr * 64 + m * 16 + fg * 4 + j;
      if (fr == 0 && grow < Mrows) {
        als[grow * 4 + head] = ps;
        ald[grow * 4 + head] = pd;
      }
    }
  }
}

// ---------------- edge softmax: per-edge normalized weights ----------------
// thread per node; w[i][4] = exp(e - m) (CSR-aligned), invS[node][4] = 1/(sum+eps)

__global__ void edge_softmax_kernel(const float* __restrict__ als, const float* __restrict__ ald,
                                    const int* __restrict__ rowptr, const int* __restrict__ col,
                                    float* __restrict__ w, float* __restrict__ invS, int Nn) {
  int node = blockIdx.x * 256 + threadIdx.x;
  if (node >= Nn) return;
  int rs = rowptr[node], re = rowptr[node + 1];
  float4 ad = *(const float4*)&ald[node * 4];
  float m0 = -INFINITY, m1 = -INFINITY, m2 = -INFINITY, m3 = -INFINITY;
  for (int i = rs; i < re; ++i) {
    int s = col[i];
    float4 a = *(const float4*)&als[s * 4];
    float e0 = a.x + ad.x; e0 = e0 > 0.f ? e0 : NEG_SLOPE * e0;
    float e1 = a.y + ad.y; e1 = e1 > 0.f ? e1 : NEG_SLOPE * e1;
    float e2 = a.z + ad.z; e2 = e2 > 0.f ? e2 : NEG_SLOPE * e2;
    float e3 = a.w + ad.w; e3 = e3 > 0.f ? e3 : NEG_SLOPE * e3;
    *(float4*)&w[(size_t)i * 4] = make_float4(e0, e1, e2, e3);
    m0 = fmaxf(m0, e0); m1 = fmaxf(m1, e1); m2 = fmaxf(m2, e2); m3 = fmaxf(m3, e3);
  }
  float S0 = 0.f, S1 = 0.f, S2 = 0.f, S3 = 0.f;
  for (int i = rs; i < re; ++i) {
    float4 e = *(const float4*)&w[(size_t)i * 4];
    float p0 = __expf(e.x - m0), p1 = __expf(e.y - m1);
    float p2 = __expf(e.z - m2), p3 = __expf(e.w - m3);
    S0 += p0; S1 += p1; S2 += p2; S3 += p3;
    *(float4*)&w[(size_t)i * 4] = make_float4(p0, p1, p2, p3);
  }
  *(float4*)&invS[node * 4] = make_float4(1.f / (S0 + 1e-16f), 1.f / (S1 + 1e-16f),
                                          1.f / (S2 + 1e-16f), 1.f / (S3 + 1e-16f));
}

// ---------------- GAT gather v2: pure weighted sum + bias + ELU ----------------
// MODE 0: write fp32. MODE 1: write bf16 hi/lo split pair (next GEMM's A operand).

template <int MODE>
__global__ __launch_bounds__(256) void gat_gather_kernel(const float* __restrict__ h,
    const float* __restrict__ w, const float* __restrict__ invS,
    const int* __restrict__ rowptr, const int* __restrict__ col,
    const float* __restrict__ bias, float* __restrict__ outf,
    u16* __restrict__ outhi, u16* __restrict__ outlo, int Nn) {
  int node = blockIdx.x * 4 + (threadIdx.x >> 6);
  int lane = threadIdx.x & 63;
  if (node >= Nn) return;
  int rs = rowptr[node], re = rowptr[node + 1];
  float acc0 = 0.f, acc1 = 0.f, acc2 = 0.f, acc3 = 0.f;
  for (int i = rs; i < re; ++i) {
    int s = col[i];
    float4 wv = *(const float4*)&w[(size_t)i * 4];
    const float* hs = h + (size_t)s * HC;
    acc0 += wv.x * hs[lane];
    acc1 += wv.y * hs[64 + lane];
    acc2 += wv.z * hs[128 + lane];
    acc3 += wv.w * hs[192 + lane];
  }
  float4 iS = *(const float4*)&invS[node * 4];
  float o[4] = {acc0 * iS.x, acc1 * iS.y, acc2 * iS.z, acc3 * iS.w};
  #pragma unroll
  for (int q = 0; q < 4; ++q) {
    float v = o[q] + bias[q * 64 + lane];
    v = v > 0.f ? v : (__expf(v) - 1.0f);     // ELU (alpha=1)
    size_t idx = (size_t)node * HC + q * 64 + lane;
    if (MODE == 0) {
      outf[idx] = v;
    } else {
      u16 hb = f2bf_rn(v);
      u16 lb = f2bf_rn(v - bf2f(hb));
      outhi[idx] = hb;
      outlo[idx] = lb;
    }
  }
}

// ---------------- pooling + MLP ----------------

__global__ void bounds_kernel(const int* __restrict__ batch, int Nn, int* __restrict__ bounds) {
  int g = threadIdx.x;
  if (g > GG) return;
  int lo = 0, hi = Nn;
  while (lo < hi) { int mid = (lo + hi) >> 1; if (batch[mid] < g) lo = mid + 1; else hi = mid; }
  bounds[g] = lo;   // lower_bound of g; bounds[64] = N
}

__global__ void pool_kernel(const float* __restrict__ X, const int* __restrict__ bounds,
                            float* __restrict__ pooled) {
  int g = blockIdx.x, split = blockIdx.y, t = threadIdx.x;
  int s = bounds[g], e = bounds[g + 1];
  int cnt = e - s;
  if (cnt <= 0) return;
  int chunk = (cnt + gridDim.y - 1) / gridDim.y;
  int s2 = s + split * chunk, e2 = min(e, s2 + chunk);
  if (s2 >= e2) return;
  float sum = 0.f;
  for (int n = s2; n < e2; ++n) sum += X[(size_t)n * HC + t];
  atomicAdd(&pooled[g * HC + t], sum);
}

__global__ __launch_bounds__(512) void mlp_kernel(const float* __restrict__ pooled,
    const int* __restrict__ bounds, const float* __restrict__ Wp1, const float* __restrict__ bp1,
    const float* __restrict__ Wp2, const float* __restrict__ bp2, float* __restrict__ out) {
  __shared__ float p[256];
  __shared__ float z1[512];
  int g = blockIdx.x, t = threadIdx.x;
  if (t < 256) {
    int cnt = bounds[g + 1] - bounds[g];
    float inv = 1.0f / (float)(cnt > 1 ? cnt : 1);
    p[t] = pooled[g * 256 + t] * inv;
  }
  __syncthreads();
  float a1 = bp1[t];
  for (int k = 0; k < 256; ++k) a1 += p[k] * Wp1[k * 512 + t];
  z1[t] = fmaxf(a1, 0.f);
  __syncthreads();
  if (t < 256) {
    float a2 = bp2[t];
    for (int k = 0; k < 512; ++k) a2 += z1[k] * Wp2[k * 256 + t];
    out[g * 256 + t] = a2;
  }
}

// ---------------- launch ----------------

static inline size_t align_up(size_t x, size_t a) { return (x + a - 1) & ~(a - 1); }

extern "C" void kernel_launch(void* const* d_in, const int* in_sizes, int n_in,
                              void* d_out, int out_size, void* d_ws, size_t ws_size,
                              hipStream_t stream) {
  const float* x    = (const float*)d_in[0];
  const int*   ei   = (const int*)d_in[1];
  const int*   batch= (const int*)d_in[2];
  const float* W1   = (const float*)d_in[3];
  const float* a1s  = (const float*)d_in[4];
  const float* a1d  = (const float*)d_in[5];
  const float* b1   = (const float*)d_in[6];
  const float* W2   = (const float*)d_in[7];
  const float* a2s  = (const float*)d_in[8];
  const float* a2d  = (const float*)d_in[9];
  const float* b2   = (const float*)d_in[10];
  const float* W3   = (const float*)d_in[11];
  const float* a3s  = (const float*)d_in[12];
  const float* a3d  = (const float*)d_in[13];
  const float* b3   = (const float*)d_in[14];
  const float* Wp1  = (const float*)d_in[15];
  const float* bp1  = (const float*)d_in[16];
  const float* Wp2  = (const float*)d_in[17];
  const float* bp2  = (const float*)d_in[18];

  const int N = in_sizes[0] / 2;       // 100000
  const int E = in_sizes[1] / 2;       // 400000
  const int Et = E + N;                // with self loops

  char* base = (char*)d_ws;
  size_t off = 0;
  auto alloc = [&](size_t bytes) { size_t o = off; off = align_up(off + bytes, 256); return o; };
  float* buf0   = (float*)(base + alloc((size_t)N * HC * 4));
  float* buf1   = (float*)(base + alloc((size_t)N * HC * 4));   // doubles as bf16 hi/lo pair
  float* als    = (float*)(base + alloc((size_t)N * 4 * 4));
  float* ald    = (float*)(base + alloc((size_t)N * 4 * 4));
  float* invS   = (float*)(base + alloc((size_t)N * 4 * 4));
  int*   rowptr = (int*)  (base + alloc((size_t)(N + 1) * 4));
  int*   col    = (int*)  (base + alloc((size_t)Et * 4));
  float* w      = (float*)(base + alloc((size_t)Et * 4 * 4));   // per-edge softmax numerators
  int*   deg    = (int*)  (base + alloc((size_t)N * 4));
  int*   cursor = (int*)  (base + alloc((size_t)N * 4));
  int*   bsum   = (int*)  (base + alloc(512 * 4));
  int*   bounds = (int*)  (base + alloc((GG + 1) * 4));
  float* pooled = (float*)(base + alloc((size_t)GG * HC * 4));
  (void)ws_size; (void)n_in; (void)out_size;

  // bf16 hi/lo views: x-pair in buf1's footprint (same bytes: 2*2B vs 4B)
  u16* xhi = (u16*)buf1;
  u16* xlo = xhi + (size_t)N * HC;
  // W2t/W3t hi/lo parked in deg/cursor space (dead after CSR build; 400 KB >= 256 KB)
  u16* W2thi = (u16*)deg;    u16* W2tlo = W2thi + 256 * 256;
  u16* W3thi = (u16*)cursor; u16* W3tlo = W3thi + 256 * 256;

  hipMemsetAsync(deg, 0, (size_t)N * 4, stream);
  hipMemsetAsync(cursor, 0, (size_t)N * 4, stream);
  hipMemsetAsync(pooled, 0, (size_t)GG * HC * 4, stream);

  // CSR by destination (same edge set for all layers)
  int ebk = (Et + 255) / 256;
  count_deg_kernel<<<ebk, 256, 0, stream>>>(ei, E, N, deg);
  int NT = (N + 255) / 256;
  scan_partial_kernel<<<NT, 256, 0, stream>>>(deg, N, rowptr, bsum);
  scan_bsum_kernel<<<1, 512, 0, stream>>>(bsum, NT);
  scan_add_kernel<<<NT, 256, 0, stream>>>(rowptr, bsum, N, Et);
  fill_csr_kernel<<<ebk, 256, 0, stream>>>(ei, E, N, rowptr, cursor, col);

  // weight conversion (deg/cursor now dead)
  convert_w_kernel<<<256, 256, 0, stream>>>(W2, W2thi, W2tlo);
  convert_w_kernel<<<256, 256, 0, stream>>>(W3, W3thi, W3tlo);

  dim3 gemm_grid(HC / GBN, (N + GBM - 1) / GBM);
  int nodeblk = (N + 3) / 4;

  // layer 1 (in=2, logits fused)
  gemm_k2_logits_kernel<<<nodeblk, 256, 0, stream>>>(x, W1, a1s, a1d, buf0, als, ald, N);
  edge_softmax_kernel<<<NT, 256, 0, stream>>>(als, ald, rowptr, col, w, invS, N);
  gat_gather_kernel<1><<<nodeblk, 256, 0, stream>>>(buf0, w, invS, rowptr, col, b1,
                                                    nullptr, xhi, xlo, N);
  // layer 2
  gemm_mfma_kernel<<<gemm_grid, 256, 0, stream>>>(xhi, xlo, W2thi, W2tlo, a2s, a2d,
                                                  buf0, als, ald, N);
  edge_softmax_kernel<<<NT, 256, 0, stream>>>(als, ald, rowptr, col, w, invS, N);
  gat_gather_kernel<1><<<nodeblk, 256, 0, stream>>>(buf0, w, invS, rowptr, col, b2,
                                                    nullptr, xhi, xlo, N);
  // layer 3
  gemm_mfma_kernel<<<gemm_grid, 256, 0, stream>>>(xhi, xlo, W3thi, W3tlo, a3s, a3d,
                                                  buf0, als, ald, N);
  edge_softmax_kernel<<<NT, 256, 0, stream>>>(als, ald, rowptr, col, w, invS, N);
  gat_gather_kernel<0><<<nodeblk, 256, 0, stream>>>(buf0, w, invS, rowptr, col, b3,
                                                    buf1, nullptr, nullptr, N);

  // pool + MLP
  bounds_kernel<<<1, 128, 0, stream>>>(batch, N, bounds);
  pool_kernel<<<dim3(GG, 8), 256, 0, stream>>>(buf1, bounds, pooled);
  mlp_kernel<<<GG, 512, 0, stream>>>(pooled, bounds, Wp1, bp1, Wp2, bp2, (float*)d_out);
}

// Round 4
// 593.687 us; speedup vs baseline: 1.5922x; 1.1093x over previous
//
#include <hip/hip_runtime.h>
#include <math.h>

#define HC 256      // H*C
#define NHEAD 4
#define NEG_SLOPE 0.2f
#define GG 64       // graphs

typedef unsigned short u16;
typedef unsigned int u32;
typedef __attribute__((ext_vector_type(8))) short short8;
typedef __attribute__((ext_vector_type(4))) float f32x4;

static __device__ inline u16 f2bf_rn(float f) {
  u32 x = __float_as_uint(f);
  u32 r = (x + 0x7fffu + ((x >> 16) & 1u)) >> 16;
  return (u16)r;
}
static __device__ inline float bf2f(u16 u) { return __uint_as_float(((u32)u) << 16); }

// ---------------- CSR build ----------------

__global__ void count_deg_kernel(const int* __restrict__ ei, int E, int Nn, int* __restrict__ deg) {
  int idx = blockIdx.x * 256 + threadIdx.x;
  int Et = E + Nn;
  if (idx >= Et) return;
  int d = (idx < E) ? ei[E + idx] : (idx - E);   // row1 of edge_index = dst; self loops appended
  atomicAdd(&deg[d], 1);
}

__global__ void scan_partial_kernel(const int* __restrict__ deg, int Nn,
                                    int* __restrict__ rowptr, int* __restrict__ bsum) {
  __shared__ int s[256];
  int t = threadIdx.x, i = blockIdx.x * 256 + t;
  int v = (i < Nn) ? deg[i] : 0;
  s[t] = v; __syncthreads();
  for (int off = 1; off < 256; off <<= 1) {
    int x = (t >= off) ? s[t - off] : 0; __syncthreads();
    s[t] += x; __syncthreads();
  }
  if (i < Nn) rowptr[i] = s[t] - v;          // exclusive within block
  if (t == 255) bsum[blockIdx.x] = s[t];     // block total
}

__global__ void scan_bsum_kernel(int* __restrict__ bsum, int nb) {
  __shared__ int s[512];
  int t = threadIdx.x;
  int v = (t < nb) ? bsum[t] : 0;
  s[t] = v; __syncthreads();
  for (int off = 1; off < 512; off <<= 1) {
    int x = (t >= off) ? s[t - off] : 0; __syncthreads();
    s[t] += x; __syncthreads();
  }
  if (t < nb) bsum[t] = s[t] - v;            // exclusive block offsets
}

__global__ void scan_add_kernel(int* __restrict__ rowptr, const int* __restrict__ bsum,
                                int Nn, int Etot) {
  int i = blockIdx.x * 256 + threadIdx.x;
  if (i < Nn) rowptr[i] += bsum[blockIdx.x];
  if (i == 0) rowptr[Nn] = Etot;
}

__global__ void fill_csr_kernel(const int* __restrict__ ei, int E, int Nn,
                                const int* __restrict__ rowptr, int* __restrict__ cursor,
                                int* __restrict__ col) {
  int idx = blockIdx.x * 256 + threadIdx.x;
  int Et = E + Nn;
  if (idx >= Et) return;
  int s, d;
  if (idx < E) { s = ei[idx]; d = ei[E + idx]; } else { s = d = idx - E; }
  int pos = atomicAdd(&cursor[d], 1);
  col[rowptr[d] + pos] = s;
}

// ---------------- W transpose + hi/lo bf16 split: Wt[n][k] ----------------

__global__ void convert_w_kernel(const float* __restrict__ W, u16* __restrict__ hi,
                                 u16* __restrict__ lo) {
  int idx = blockIdx.x * 256 + threadIdx.x;    // 65536 threads
  if (idx >= 256 * 256) return;
  int k = idx >> 8, n = idx & 255;             // coalesced read of W[k][n]
  float v = W[idx];
  u16 h = f2bf_rn(v);
  u16 l = f2bf_rn(v - bf2f(h));
  hi[n * 256 + k] = h;
  lo[n * 256 + k] = l;
}

// ---------------- layer 1: K=2 GEMM fused with attention logits ----------------
// wave per node; h written as bf16 (message path); logits from fp32 values.

__global__ __launch_bounds__(256) void gemm_k2_logits_kernel(
    const float* __restrict__ x, const float* __restrict__ W,
    const float* __restrict__ as_, const float* __restrict__ ad_,
    u16* __restrict__ h16, float* __restrict__ als, float* __restrict__ ald, int Nn) {
  int node = blockIdx.x * 4 + (threadIdx.x >> 6);
  int lane = threadIdx.x & 63;
  if (node >= Nn) return;
  float x0 = x[node * 2], x1 = x[node * 2 + 1];
  float ps[4], pd[4];
  #pragma unroll
  for (int q = 0; q < 4; ++q) {
    int c = q * 64 + lane;
    float o = x0 * W[c] + x1 * W[256 + c];
    h16[(size_t)node * HC + c] = f2bf_rn(o);
    ps[q] = o * as_[c];
    pd[q] = o * ad_[c];
  }
  #pragma unroll
  for (int off = 32; off >= 1; off >>= 1) {
    #pragma unroll
    for (int q = 0; q < 4; ++q) {
      ps[q] += __shfl_xor(ps[q], off, 64);
      pd[q] += __shfl_xor(pd[q], off, 64);
    }
  }
  if (lane == 0) {
    *(float4*)&als[node * 4] = make_float4(ps[0], ps[1], ps[2], ps[3]);
    *(float4*)&ald[node * 4] = make_float4(pd[0], pd[1], pd[2], pd[3]);
  }
}

// ---------------- split-bf16 MFMA GEMM + fused attention logits ----------------
// A as hi/lo bf16 [M][256]; B transposed hi/lo bf16 Wt[n][k].
// C = Ahi@Bhi + Ahi@Blo + Alo@Bhi, written as bf16 (message path only).
// Epilogue also emits als/ald from the fp32 accumulators (head = bc*2 + wc).

#define GBM 128
#define GBN 128
#define GBK 32
#define LSTR 40   // padded LDS row stride (shorts); 80 B = 5*16 -> 16B-aligned rows

__global__ __launch_bounds__(256) void gemm_mfma_kernel(
    const u16* __restrict__ Ahi, const u16* __restrict__ Alo,
    const u16* __restrict__ Bhi, const u16* __restrict__ Blo,
    const float* __restrict__ as_, const float* __restrict__ ad_,
    u16* __restrict__ C16, float* __restrict__ als, float* __restrict__ ald, int Mrows) {
  __shared__ __align__(16) u16 As[2][GBM][LSTR];
  __shared__ __align__(16) u16 Bs[2][GBN][LSTR];
  int bc = blockIdx.x, br = blockIdx.y;
  int tid = threadIdx.x;
  int wid = tid >> 6, lane = tid & 63;
  int wr = wid >> 1, wc = wid & 1;             // 2x2 wave grid, 64x64 per wave
  int row0 = br * GBM, col0 = bc * GBN;
  int fr = lane & 15, fg = lane >> 4;

  f32x4 acc[4][4];
  #pragma unroll
  for (int m = 0; m < 4; ++m)
    #pragma unroll
    for (int n = 0; n < 4; ++n) acc[m][n] = (f32x4){0.f, 0.f, 0.f, 0.f};

  for (int k0 = 0; k0 < 256; k0 += GBK) {
    #pragma unroll
    for (int l = 0; l < 2; ++l) {
      int u = tid + l * 256;                   // 0..511
      int r = u >> 2, kc = (u & 3) << 3;       // row, k-chunk*8
      int gr = row0 + r; if (gr >= Mrows) gr = Mrows - 1;
      size_t ga = (size_t)gr * 256 + k0 + kc;
      *(uint4*)&As[0][r][kc] = *(const uint4*)&Ahi[ga];
      *(uint4*)&As[1][r][kc] = *(const uint4*)&Alo[ga];
      size_t gb = (size_t)(col0 + r) * 256 + k0 + kc;
      *(uint4*)&Bs[0][r][kc] = *(const uint4*)&Bhi[gb];
      *(uint4*)&Bs[1][r][kc] = *(const uint4*)&Blo[gb];
    }
    __syncthreads();

    short8 ah[4], al[4], bh[4], bl[4];
    #pragma unroll
    for (int m = 0; m < 4; ++m) {
      int r = wr * 64 + m * 16 + fr;
      ah[m] = *(const short8*)&As[0][r][fg * 8];
      al[m] = *(const short8*)&As[1][r][fg * 8];
    }
    #pragma unroll
    for (int n = 0; n < 4; ++n) {
      int c = wc * 64 + n * 16 + fr;
      bh[n] = *(const short8*)&Bs[0][c][fg * 8];
      bl[n] = *(const short8*)&Bs[1][c][fg * 8];
    }
    #pragma unroll
    for (int m = 0; m < 4; ++m)
      #pragma unroll
      for (int n = 0; n < 4; ++n) {
        acc[m][n] = __builtin_amdgcn_mfma_f32_16x16x32_bf16(ah[m], bh[n], acc[m][n], 0, 0, 0);
        acc[m][n] = __builtin_amdgcn_mfma_f32_16x16x32_bf16(ah[m], bl[n], acc[m][n], 0, 0, 0);
        acc[m][n] = __builtin_amdgcn_mfma_f32_16x16x32_bf16(al[m], bh[n], acc[m][n], 0, 0, 0);
      }
    __syncthreads();
  }

  // C write (bf16): col=lane&15 within frag, row=(lane>>4)*4+j
  #pragma unroll
  for (int m = 0; m < 4; ++m) {
    #pragma unroll
    for (int n = 0; n < 4; ++n) {
      int col = col0 + wc * 64 + n * 16 + fr;
      #pragma unroll
      for (int j = 0; j < 4; ++j) {
        int row = row0 + wr * 64 + m * 16 + fg * 4 + j;
        if (row < Mrows) C16[(size_t)row * 256 + col] = f2bf_rn(acc[m][n][j]);
      }
    }
  }

  // fused logits: this wave's cols = one head
  int head = bc * 2 + wc;
  float asv[4], adv[4];
  #pragma unroll
  for (int n = 0; n < 4; ++n) {
    asv[n] = as_[head * 64 + n * 16 + fr];
    adv[n] = ad_[head * 64 + n * 16 + fr];
  }
  #pragma unroll
  for (int m = 0; m < 4; ++m) {
    #pragma unroll
    for (int j = 0; j < 4; ++j) {
      float ps = 0.f, pd = 0.f;
      #pragma unroll
      for (int n = 0; n < 4; ++n) {
        ps += acc[m][n][j] * asv[n];
        pd += acc[m][n][j] * adv[n];
      }
      #pragma unroll
      for (int off = 1; off < 16; off <<= 1) {
        ps += __shfl_xor(ps, off, 64);
        pd += __shfl_xor(pd, off, 64);
      }
      int grow = row0 + wr * 64 + m * 16 + fg * 4 + j;
      if (fr == 0 && grow < Mrows) {
        als[grow * 4 + head] = ps;
        ald[grow * 4 + head] = pd;
      }
    }
  }
}

// ---------------- fused GAT gather: edge softmax (flash-style) + weighted sum ----------------
// wave per node. Per 64-edge chunk: lanes 0..cnt-1 compute one edge's logits,
// wave-reduce max/sum, online-rescale (M,S,acc), then broadcast weights via
// __shfl for the per-channel accumulation. No LDS, no block barriers.
// MODE 0: write bf16 hi only (feeds pool). MODE 1: write bf16 hi/lo pair (next GEMM A).

template <int MODE>
__global__ __launch_bounds__(256) void gat_gather_kernel(const u16* __restrict__ h16,
    const float* __restrict__ als, const float* __restrict__ ald,
    const int* __restrict__ rowptr, const int* __restrict__ col,
    const float* __restrict__ bias,
    u16* __restrict__ outhi, u16* __restrict__ outlo, int Nn) {
  int node = blockIdx.x * 4 + (threadIdx.x >> 6);
  int lane = threadIdx.x & 63;
  if (node >= Nn) return;
  int rs = rowptr[node], re = rowptr[node + 1];
  float4 ad = *(const float4*)&ald[node * 4];
  float adv[4] = {ad.x, ad.y, ad.z, ad.w};
  float M[4], S[4], acc[4];
  #pragma unroll
  for (int q = 0; q < 4; ++q) { M[q] = -INFINITY; S[q] = 0.f; acc[q] = 0.f; }

  for (int base = rs; base < re; base += 64) {
    int cnt = re - base; if (cnt > 64) cnt = 64;
    bool act = lane < cnt;
    int s = act ? col[base + lane] : 0;
    float4 a = *(const float4*)&als[(size_t)s * 4];
    float e[4] = {a.x + adv[0], a.y + adv[1], a.z + adv[2], a.w + adv[3]};
    float cm[4], p[4], psum[4];
    #pragma unroll
    for (int q = 0; q < 4; ++q) {
      float v = e[q];
      v = v > 0.f ? v : NEG_SLOPE * v;
      e[q] = act ? v : -INFINITY;
      cm[q] = e[q];
    }
    #pragma unroll
    for (int off = 32; off >= 1; off >>= 1)
      #pragma unroll
      for (int q = 0; q < 4; ++q) cm[q] = fmaxf(cm[q], __shfl_xor(cm[q], off, 64));
    #pragma unroll
    for (int q = 0; q < 4; ++q) {
      float nm = fmaxf(M[q], cm[q]);
      float resc = __expf(M[q] - nm);          // first chunk: exp(-inf)=0
      p[q] = act ? __expf(e[q] - nm) : 0.f;
      psum[q] = p[q];
      S[q] *= resc;
      acc[q] *= resc;
      M[q] = nm;
    }
    #pragma unroll
    for (int off = 32; off >= 1; off >>= 1)
      #pragma unroll
      for (int q = 0; q < 4; ++q) psum[q] += __shfl_xor(psum[q], off, 64);
    #pragma unroll
    for (int q = 0; q < 4; ++q) S[q] += psum[q];

    for (int j = 0; j < cnt; ++j) {
      int sj = __shfl(s, j, 64);
      float w0 = __shfl(p[0], j, 64);
      float w1 = __shfl(p[1], j, 64);
      float w2 = __shfl(p[2], j, 64);
      float w3 = __shfl(p[3], j, 64);
      const u16* hr = h16 + (size_t)sj * HC;
      acc[0] += w0 * bf2f(hr[lane]);
      acc[1] += w1 * bf2f(hr[64 + lane]);
      acc[2] += w2 * bf2f(hr[128 + lane]);
      acc[3] += w3 * bf2f(hr[192 + lane]);
    }
  }

  #pragma unroll
  for (int q = 0; q < 4; ++q) {
    float v = acc[q] / (S[q] + 1e-16f) + bias[q * 64 + lane];
    v = v > 0.f ? v : (__expf(v) - 1.0f);     // ELU (alpha=1)
    size_t idx = (size_t)node * HC + q * 64 + lane;
    if (MODE == 0) {
      outhi[idx] = f2bf_rn(v);
    } else {
      u16 hb = f2bf_rn(v);
      u16 lb = f2bf_rn(v - bf2f(hb));
      outhi[idx] = hb;
      outlo[idx] = lb;
    }
  }
}

// ---------------- pooling + MLP ----------------

__global__ void bounds_kernel(const int* __restrict__ batch, int Nn, int* __restrict__ bounds) {
  int g = threadIdx.x;
  if (g > GG) return;
  int lo = 0, hi = Nn;
  while (lo < hi) { int mid = (lo + hi) >> 1; if (batch[mid] < g) lo = mid + 1; else hi = mid; }
  bounds[g] = lo;   // lower_bound of g; bounds[64] = N
}

__global__ void pool_kernel(const u16* __restrict__ X, const int* __restrict__ bounds,
                            float* __restrict__ pooled) {
  int g = blockIdx.x, split = blockIdx.y, t = threadIdx.x;
  int s = bounds[g], e = bounds[g + 1];
  int cnt = e - s;
  if (cnt <= 0) return;
  int chunk = (cnt + gridDim.y - 1) / gridDim.y;
  int s2 = s + split * chunk, e2 = min(e, s2 + chunk);
  if (s2 >= e2) return;
  float sum = 0.f;
  for (int n = s2; n < e2; ++n) sum += bf2f(X[(size_t)n * HC + t]);
  atomicAdd(&pooled[g * HC + t], sum);
}

__global__ __launch_bounds__(512) void mlp_kernel(const float* __restrict__ pooled,
    const int* __restrict__ bounds, const float* __restrict__ Wp1, const float* __restrict__ bp1,
    const float* __restrict__ Wp2, const float* __restrict__ bp2, float* __restrict__ out) {
  __shared__ float p[256];
  __shared__ float z1[512];
  int g = blockIdx.x, t = threadIdx.x;
  if (t < 256) {
    int cnt = bounds[g + 1] - bounds[g];
    float inv = 1.0f / (float)(cnt > 1 ? cnt : 1);
    p[t] = pooled[g * 256 + t] * inv;
  }
  __syncthreads();
  float a1 = bp1[t];
  for (int k = 0; k < 256; ++k) a1 += p[k] * Wp1[k * 512 + t];
  z1[t] = fmaxf(a1, 0.f);
  __syncthreads();
  if (t < 256) {
    float a2 = bp2[t];
    for (int k = 0; k < 512; ++k) a2 += z1[k] * Wp2[k * 256 + t];
    out[g * 256 + t] = a2;
  }
}

// ---------------- launch ----------------

static inline size_t align_up(size_t x, size_t a) { return (x + a - 1) & ~(a - 1); }

extern "C" void kernel_launch(void* const* d_in, const int* in_sizes, int n_in,
                              void* d_out, int out_size, void* d_ws, size_t ws_size,
                              hipStream_t stream) {
  const float* x    = (const float*)d_in[0];
  const int*   ei   = (const int*)d_in[1];
  const int*   batch= (const int*)d_in[2];
  const float* W1   = (const float*)d_in[3];
  const float* a1s  = (const float*)d_in[4];
  const float* a1d  = (const float*)d_in[5];
  const float* b1   = (const float*)d_in[6];
  const float* W2   = (const float*)d_in[7];
  const float* a2s  = (const float*)d_in[8];
  const float* a2d  = (const float*)d_in[9];
  const float* b2   = (const float*)d_in[10];
  const float* W3   = (const float*)d_in[11];
  const float* a3s  = (const float*)d_in[12];
  const float* a3d  = (const float*)d_in[13];
  const float* b3   = (const float*)d_in[14];
  const float* Wp1  = (const float*)d_in[15];
  const float* bp1  = (const float*)d_in[16];
  const float* Wp2  = (const float*)d_in[17];
  const float* bp2  = (const float*)d_in[18];

  const int N = in_sizes[0] / 2;       // 100000
  const int E = in_sizes[1] / 2;       // 400000
  const int Et = E + N;                // with self loops

  char* base = (char*)d_ws;
  size_t off = 0;
  auto alloc = [&](size_t bytes) { size_t o = off; off = align_up(off + bytes, 256); return o; };
  u16*   h16    = (u16*)  (base + alloc((size_t)N * HC * 2));   // message-path h (bf16)
  u16*   xhi    = (u16*)  (base + alloc((size_t)N * HC * 2));   // gather out hi
  u16*   xlo    = (u16*)  (base + alloc((size_t)N * HC * 2));   // gather out lo
  float* als    = (float*)(base + alloc((size_t)N * 4 * 4));
  float* ald    = (float*)(base + alloc((size_t)N * 4 * 4));
  int*   rowptr = (int*)  (base + alloc((size_t)(N + 1) * 4));
  int*   col    = (int*)  (base + alloc((size_t)Et * 4));
  int*   deg    = (int*)  (base + alloc((size_t)N * 4));
  int*   cursor = (int*)  (base + alloc((size_t)N * 4));
  int*   bsum   = (int*)  (base + alloc(512 * 4));
  int*   bounds = (int*)  (base + alloc((GG + 1) * 4));
  float* pooled = (float*)(base + alloc((size_t)GG * HC * 4));
  (void)ws_size; (void)n_in; (void)out_size;

  // W2t/W3t hi/lo parked in deg/cursor space (dead after CSR build; 400 KB >= 256 KB)
  u16* W2thi = (u16*)deg;    u16* W2tlo = W2thi + 256 * 256;
  u16* W3thi = (u16*)cursor; u16* W3tlo = W3thi + 256 * 256;

  hipMemsetAsync(deg, 0, (size_t)N * 4, stream);
  hipMemsetAsync(cursor, 0, (size_t)N * 4, stream);
  hipMemsetAsync(pooled, 0, (size_t)GG * HC * 4, stream);

  // CSR by destination (same edge set for all layers)
  int ebk = (Et + 255) / 256;
  count_deg_kernel<<<ebk, 256, 0, stream>>>(ei, E, N, deg);
  int NT = (N + 255) / 256;
  scan_partial_kernel<<<NT, 256, 0, stream>>>(deg, N, rowptr, bsum);
  scan_bsum_kernel<<<1, 512, 0, stream>>>(bsum, NT);
  scan_add_kernel<<<NT, 256, 0, stream>>>(rowptr, bsum, N, Et);
  fill_csr_kernel<<<ebk, 256, 0, stream>>>(ei, E, N, rowptr, cursor, col);

  // weight conversion (deg/cursor now dead)
  convert_w_kernel<<<256, 256, 0, stream>>>(W2, W2thi, W2tlo);
  convert_w_kernel<<<256, 256, 0, stream>>>(W3, W3thi, W3tlo);

  dim3 gemm_grid(HC / GBN, (N + GBM - 1) / GBM);
  int nodeblk = (N + 3) / 4;

  // layer 1 (in=2, logits fused)
  gemm_k2_logits_kernel<<<nodeblk, 256, 0, stream>>>(x, W1, a1s, a1d, h16, als, ald, N);
  gat_gather_kernel<1><<<nodeblk, 256, 0, stream>>>(h16, als, ald, rowptr, col, b1,
                                                    xhi, xlo, N);
  // layer 2
  gemm_mfma_kernel<<<gemm_grid, 256, 0, stream>>>(xhi, xlo, W2thi, W2tlo, a2s, a2d,
                                                  h16, als, ald, N);
  gat_gather_kernel<1><<<nodeblk, 256, 0, stream>>>(h16, als, ald, rowptr, col, b2,
                                                    xhi, xlo, N);
  // layer 3
  gemm_mfma_kernel<<<gemm_grid, 256, 0, stream>>>(xhi, xlo, W3thi, W3tlo, a3s, a3d,
                                                  h16, als, ald, N);
  gat_gather_kernel<0><<<nodeblk, 256, 0, stream>>>(h16, als, ald, rowptr, col, b3,
                                                    xhi, nullptr, N);

  // pool + MLP
  bounds_kernel<<<1, 128, 0, stream>>>(batch, N, bounds);
  pool_kernel<<<dim3(GG, 8), 256, 0, stream>>>(xhi, bounds, pooled);
  mlp_kernel<<<GG, 512, 0, stream>>>(pooled, bounds, Wp1, bp1, Wp2, bp2, (float*)d_out);
}

// Round 5
// 528.496 us; speedup vs baseline: 1.7886x; 1.1234x over previous
//
#include <hip/hip_runtime.h>
#include <math.h>

#define HC 256      // H*C
#define NHEAD 4
#define NEG_SLOPE 0.2f
#define GG 64       // graphs

typedef unsigned short u16;
typedef unsigned int u32;
typedef __attribute__((ext_vector_type(8))) short short8;
typedef __attribute__((ext_vector_type(4))) float f32x4;

static __device__ inline u16 f2bf_rn(float f) {
  u32 x = __float_as_uint(f);
  u32 r = (x + 0x7fffu + ((x >> 16) & 1u)) >> 16;
  return (u16)r;
}
static __device__ inline float bf2f(u16 u) { return __uint_as_float(((u32)u) << 16); }

// ---------------- CSR build ----------------

__global__ void count_deg_kernel(const int* __restrict__ ei, int E, int Nn, int* __restrict__ deg) {
  int idx = blockIdx.x * 256 + threadIdx.x;
  int Et = E + Nn;
  if (idx >= Et) return;
  int d = (idx < E) ? ei[E + idx] : (idx - E);   // row1 of edge_index = dst; self loops appended
  atomicAdd(&deg[d], 1);
}

__global__ void scan_partial_kernel(const int* __restrict__ deg, int Nn,
                                    int* __restrict__ rowptr, int* __restrict__ bsum) {
  __shared__ int s[256];
  int t = threadIdx.x, i = blockIdx.x * 256 + t;
  int v = (i < Nn) ? deg[i] : 0;
  s[t] = v; __syncthreads();
  for (int off = 1; off < 256; off <<= 1) {
    int x = (t >= off) ? s[t - off] : 0; __syncthreads();
    s[t] += x; __syncthreads();
  }
  if (i < Nn) rowptr[i] = s[t] - v;          // exclusive within block
  if (t == 255) bsum[blockIdx.x] = s[t];     // block total
}

__global__ void scan_bsum_kernel(int* __restrict__ bsum, int nb) {
  __shared__ int s[512];
  int t = threadIdx.x;
  int v = (t < nb) ? bsum[t] : 0;
  s[t] = v; __syncthreads();
  for (int off = 1; off < 512; off <<= 1) {
    int x = (t >= off) ? s[t - off] : 0; __syncthreads();
    s[t] += x; __syncthreads();
  }
  if (t < nb) bsum[t] = s[t] - v;            // exclusive block offsets
}

__global__ void scan_add_kernel(int* __restrict__ rowptr, const int* __restrict__ bsum,
                                int Nn, int Etot) {
  int i = blockIdx.x * 256 + threadIdx.x;
  if (i < Nn) rowptr[i] += bsum[blockIdx.x];
  if (i == 0) rowptr[Nn] = Etot;
}

__global__ void fill_csr_kernel(const int* __restrict__ ei, int E, int Nn,
                                const int* __restrict__ rowptr, int* __restrict__ cursor,
                                int* __restrict__ col) {
  int idx = blockIdx.x * 256 + threadIdx.x;
  int Et = E + Nn;
  if (idx >= Et) return;
  int s, d;
  if (idx < E) { s = ei[idx]; d = ei[E + idx]; } else { s = d = idx - E; }
  int pos = atomicAdd(&cursor[d], 1);
  col[rowptr[d] + pos] = s;
}

// ---------------- W transpose + hi/lo bf16 split: Wt[n][k] ----------------

__global__ void convert_w_kernel(const float* __restrict__ W, u16* __restrict__ hi,
                                 u16* __restrict__ lo) {
  int idx = blockIdx.x * 256 + threadIdx.x;    // 65536 threads
  if (idx >= 256 * 256) return;
  int k = idx >> 8, n = idx & 255;             // coalesced read of W[k][n]
  float v = W[idx];
  u16 h = f2bf_rn(v);
  u16 l = f2bf_rn(v - bf2f(h));
  hi[n * 256 + k] = h;
  lo[n * 256 + k] = l;
}

// ---------------- layer 1: K=2 GEMM fused with attention logits ----------------
// wave per node; h written as bf16 (message path); logits from fp32 values.

__global__ __launch_bounds__(256) void gemm_k2_logits_kernel(
    const float* __restrict__ x, const float* __restrict__ W,
    const float* __restrict__ as_, const float* __restrict__ ad_,
    u16* __restrict__ h16, float* __restrict__ als, float* __restrict__ ald, int Nn) {
  int node = blockIdx.x * 4 + (threadIdx.x >> 6);
  int lane = threadIdx.x & 63;
  if (node >= Nn) return;
  float x0 = x[node * 2], x1 = x[node * 2 + 1];
  float ps[4], pd[4];
  #pragma unroll
  for (int q = 0; q < 4; ++q) {
    int c = q * 64 + lane;
    float o = x0 * W[c] + x1 * W[256 + c];
    h16[(size_t)node * HC + c] = f2bf_rn(o);
    ps[q] = o * as_[c];
    pd[q] = o * ad_[c];
  }
  #pragma unroll
  for (int off = 32; off >= 1; off >>= 1) {
    #pragma unroll
    for (int q = 0; q < 4; ++q) {
      ps[q] += __shfl_xor(ps[q], off, 64);
      pd[q] += __shfl_xor(pd[q], off, 64);
    }
  }
  if (lane == 0) {
    *(float4*)&als[node * 4] = make_float4(ps[0], ps[1], ps[2], ps[3]);
    *(float4*)&ald[node * 4] = make_float4(pd[0], pd[1], pd[2], pd[3]);
  }
}

// ---------------- bf16-A x split-bf16-W MFMA GEMM + fused attention logits ----------------
// A bf16 [M][256]; B transposed hi/lo bf16 Wt[n][k].
// C = A@Bhi + A@Blo = A@W (exact W), A carries 2^-9 rounding.
// C written bf16 (message path); logits from fp32 accumulators (head = bc*2+wc).

#define GBM 128
#define GBN 128
#define GBK 32
#define LSTR 40   // padded LDS row stride (shorts); 80 B = 5*16 -> 16B-aligned rows

__global__ __launch_bounds__(256) void gemm_mfma_kernel(
    const u16* __restrict__ A,
    const u16* __restrict__ Bhi, const u16* __restrict__ Blo,
    const float* __restrict__ as_, const float* __restrict__ ad_,
    u16* __restrict__ C16, float* __restrict__ als, float* __restrict__ ald, int Mrows) {
  __shared__ __align__(16) u16 As[GBM][LSTR];
  __shared__ __align__(16) u16 Bs[2][GBN][LSTR];
  int bc = blockIdx.x, br = blockIdx.y;
  int tid = threadIdx.x;
  int wid = tid >> 6, lane = tid & 63;
  int wr = wid >> 1, wc = wid & 1;             // 2x2 wave grid, 64x64 per wave
  int row0 = br * GBM, col0 = bc * GBN;
  int fr = lane & 15, fg = lane >> 4;

  f32x4 acc[4][4];
  #pragma unroll
  for (int m = 0; m < 4; ++m)
    #pragma unroll
    for (int n = 0; n < 4; ++n) acc[m][n] = (f32x4){0.f, 0.f, 0.f, 0.f};

  for (int k0 = 0; k0 < 256; k0 += GBK) {
    #pragma unroll
    for (int l = 0; l < 2; ++l) {
      int u = tid + l * 256;                   // 0..511
      int r = u >> 2, kc = (u & 3) << 3;       // row, k-chunk*8
      int gr = row0 + r; if (gr >= Mrows) gr = Mrows - 1;
      *(uint4*)&As[r][kc] = *(const uint4*)&A[(size_t)gr * 256 + k0 + kc];
      size_t gb = (size_t)(col0 + r) * 256 + k0 + kc;
      *(uint4*)&Bs[0][r][kc] = *(const uint4*)&Bhi[gb];
      *(uint4*)&Bs[1][r][kc] = *(const uint4*)&Blo[gb];
    }
    __syncthreads();

    short8 a[4], bh[4], bl[4];
    #pragma unroll
    for (int m = 0; m < 4; ++m)
      a[m] = *(const short8*)&As[wr * 64 + m * 16 + fr][fg * 8];
    #pragma unroll
    for (int n = 0; n < 4; ++n) {
      int c = wc * 64 + n * 16 + fr;
      bh[n] = *(const short8*)&Bs[0][c][fg * 8];
      bl[n] = *(const short8*)&Bs[1][c][fg * 8];
    }
    #pragma unroll
    for (int m = 0; m < 4; ++m)
      #pragma unroll
      for (int n = 0; n < 4; ++n) {
        acc[m][n] = __builtin_amdgcn_mfma_f32_16x16x32_bf16(a[m], bh[n], acc[m][n], 0, 0, 0);
        acc[m][n] = __builtin_amdgcn_mfma_f32_16x16x32_bf16(a[m], bl[n], acc[m][n], 0, 0, 0);
      }
    __syncthreads();
  }

  // C write (bf16): col=lane&15 within frag, row=(lane>>4)*4+j
  #pragma unroll
  for (int m = 0; m < 4; ++m) {
    #pragma unroll
    for (int n = 0; n < 4; ++n) {
      int col = col0 + wc * 64 + n * 16 + fr;
      #pragma unroll
      for (int j = 0; j < 4; ++j) {
        int row = row0 + wr * 64 + m * 16 + fg * 4 + j;
        if (row < Mrows) C16[(size_t)row * 256 + col] = f2bf_rn(acc[m][n][j]);
      }
    }
  }

  // fused logits: this wave's cols = one head
  int head = bc * 2 + wc;
  float asv[4], adv[4];
  #pragma unroll
  for (int n = 0; n < 4; ++n) {
    asv[n] = as_[head * 64 + n * 16 + fr];
    adv[n] = ad_[head * 64 + n * 16 + fr];
  }
  #pragma unroll
  for (int m = 0; m < 4; ++m) {
    #pragma unroll
    for (int j = 0; j < 4; ++j) {
      float ps = 0.f, pd = 0.f;
      #pragma unroll
      for (int n = 0; n < 4; ++n) {
        ps += acc[m][n][j] * asv[n];
        pd += acc[m][n][j] * adv[n];
      }
      #pragma unroll
      for (int off = 1; off < 16; off <<= 1) {
        ps += __shfl_xor(ps, off, 64);
        pd += __shfl_xor(pd, off, 64);
      }
      int grow = row0 + wr * 64 + m * 16 + fg * 4 + j;
      if (fr == 0 && grow < Mrows) {
        als[grow * 4 + head] = ps;
        ald[grow * 4 + head] = pd;
      }
    }
  }
}

// ---------------- edge softmax: per-edge normalized weights (thread per node) ----------------

__global__ void edge_softmax_kernel(const float* __restrict__ als, const float* __restrict__ ald,
                                    const int* __restrict__ rowptr, const int* __restrict__ col,
                                    float* __restrict__ w, float* __restrict__ invS, int Nn) {
  int node = blockIdx.x * 256 + threadIdx.x;
  if (node >= Nn) return;
  int rs = rowptr[node], re = rowptr[node + 1];
  float4 ad = *(const float4*)&ald[node * 4];
  float m0 = -INFINITY, m1 = -INFINITY, m2 = -INFINITY, m3 = -INFINITY;
  for (int i = rs; i < re; ++i) {
    int s = col[i];
    float4 a = *(const float4*)&als[(size_t)s * 4];
    float e0 = a.x + ad.x; e0 = e0 > 0.f ? e0 : NEG_SLOPE * e0;
    float e1 = a.y + ad.y; e1 = e1 > 0.f ? e1 : NEG_SLOPE * e1;
    float e2 = a.z + ad.z; e2 = e2 > 0.f ? e2 : NEG_SLOPE * e2;
    float e3 = a.w + ad.w; e3 = e3 > 0.f ? e3 : NEG_SLOPE * e3;
    *(float4*)&w[(size_t)i * 4] = make_float4(e0, e1, e2, e3);
    m0 = fmaxf(m0, e0); m1 = fmaxf(m1, e1); m2 = fmaxf(m2, e2); m3 = fmaxf(m3, e3);
  }
  float S0 = 0.f, S1 = 0.f, S2 = 0.f, S3 = 0.f;
  for (int i = rs; i < re; ++i) {
    float4 e = *(const float4*)&w[(size_t)i * 4];
    float p0 = __expf(e.x - m0), p1 = __expf(e.y - m1);
    float p2 = __expf(e.z - m2), p3 = __expf(e.w - m3);
    S0 += p0; S1 += p1; S2 += p2; S3 += p3;
    *(float4*)&w[(size_t)i * 4] = make_float4(p0, p1, p2, p3);
  }
  *(float4*)&invS[node * 4] = make_float4(1.f / (S0 + 1e-16f), 1.f / (S1 + 1e-16f),
                                          1.f / (S2 + 1e-16f), 1.f / (S3 + 1e-16f));
}

// ---------------- GAT gather v3: weighted sum, channel-pair dwords ----------------
// wave per node (scalarized); lane owns channels {2l, 2l+1, 128+2l, 128+2l+1}.
// Per edge: uniform col + uniform float4 w + 2 per-lane dword loads + 4 FMA.
// Output: bf16 packed u32 stores (feeds next GEMM's bf16 A, or the pool).

__global__ __launch_bounds__(256) void gat_gather_kernel(const u16* __restrict__ h16,
    const float* __restrict__ w, const float* __restrict__ invS,
    const int* __restrict__ rowptr, const int* __restrict__ col,
    const float* __restrict__ bias, u16* __restrict__ out16, int Nn) {
  int node = __builtin_amdgcn_readfirstlane(blockIdx.x * 4 + (threadIdx.x >> 6));
  int lane = threadIdx.x & 63;
  if (node >= Nn) return;
  int rs = rowptr[node], re = rowptr[node + 1];
  int hsel = lane >> 5;                       // head parity selector
  float a0 = 0.f, a1 = 0.f, a2 = 0.f, a3 = 0.f;
  const u32* h32 = (const u32*)h16;
  for (int i = rs; i < re; ++i) {
    int s = col[i];
    float4 wv = *(const float4*)&w[(size_t)i * 4];
    float wA = hsel ? wv.y : wv.x;
    float wB = hsel ? wv.w : wv.z;
    const u32* hr = h32 + (size_t)s * 128;
    u32 pa = hr[lane];                        // ch 2l, 2l+1   (head l>>5)
    u32 pb = hr[64 + lane];                   // ch 128+2l, 128+2l+1 (head 2+(l>>5))
    a0 += wA * __uint_as_float(pa << 16);
    a1 += wA * __uint_as_float(pa & 0xffff0000u);
    a2 += wB * __uint_as_float(pb << 16);
    a3 += wB * __uint_as_float(pb & 0xffff0000u);
  }
  float4 iS = *(const float4*)&invS[node * 4];
  float isA = hsel ? iS.y : iS.x;
  float isB = hsel ? iS.w : iS.z;
  float2 bA = *(const float2*)&bias[2 * lane];
  float2 bB = *(const float2*)&bias[128 + 2 * lane];
  float o0 = a0 * isA + bA.x;
  float o1 = a1 * isA + bA.y;
  float o2 = a2 * isB + bB.x;
  float o3 = a3 * isB + bB.y;
  o0 = o0 > 0.f ? o0 : (__expf(o0) - 1.0f);   // ELU (alpha=1)
  o1 = o1 > 0.f ? o1 : (__expf(o1) - 1.0f);
  o2 = o2 > 0.f ? o2 : (__expf(o2) - 1.0f);
  o3 = o3 > 0.f ? o3 : (__expf(o3) - 1.0f);
  u32* o32 = (u32*)out16;
  o32[(size_t)node * 128 + lane]      = (u32)f2bf_rn(o0) | ((u32)f2bf_rn(o1) << 16);
  o32[(size_t)node * 128 + 64 + lane] = (u32)f2bf_rn(o2) | ((u32)f2bf_rn(o3) << 16);
}

// ---------------- pooling + MLP ----------------

__global__ void bounds_kernel(const int* __restrict__ batch, int Nn, int* __restrict__ bounds) {
  int g = threadIdx.x;
  if (g > GG) return;
  int lo = 0, hi = Nn;
  while (lo < hi) { int mid = (lo + hi) >> 1; if (batch[mid] < g) lo = mid + 1; else hi = mid; }
  bounds[g] = lo;   // lower_bound of g; bounds[64] = N
}

__global__ void pool_kernel(const u16* __restrict__ X, const int* __restrict__ bounds,
                            float* __restrict__ pooled) {
  int g = blockIdx.x, split = blockIdx.y, t = threadIdx.x;
  int s = bounds[g], e = bounds[g + 1];
  int cnt = e - s;
  if (cnt <= 0) return;
  int chunk = (cnt + gridDim.y - 1) / gridDim.y;
  int s2 = s + split * chunk, e2 = min(e, s2 + chunk);
  if (s2 >= e2) return;
  float sum = 0.f;
  for (int n = s2; n < e2; ++n) sum += bf2f(X[(size_t)n * HC + t]);
  atomicAdd(&pooled[g * HC + t], sum);
}

__global__ __launch_bounds__(512) void mlp_kernel(const float* __restrict__ pooled,
    const int* __restrict__ bounds, const float* __restrict__ Wp1, const float* __restrict__ bp1,
    const float* __restrict__ Wp2, const float* __restrict__ bp2, float* __restrict__ out) {
  __shared__ float p[256];
  __shared__ float z1[512];
  int g = blockIdx.x, t = threadIdx.x;
  if (t < 256) {
    int cnt = bounds[g + 1] - bounds[g];
    float inv = 1.0f / (float)(cnt > 1 ? cnt : 1);
    p[t] = pooled[g * 256 + t] * inv;
  }
  __syncthreads();
  float a1 = bp1[t];
  for (int k = 0; k < 256; ++k) a1 += p[k] * Wp1[k * 512 + t];
  z1[t] = fmaxf(a1, 0.f);
  __syncthreads();
  if (t < 256) {
    float a2 = bp2[t];
    for (int k = 0; k < 512; ++k) a2 += z1[k] * Wp2[k * 256 + t];
    out[g * 256 + t] = a2;
  }
}

// ---------------- launch ----------------

static inline size_t align_up(size_t x, size_t a) { return (x + a - 1) & ~(a - 1); }

extern "C" void kernel_launch(void* const* d_in, const int* in_sizes, int n_in,
                              void* d_out, int out_size, void* d_ws, size_t ws_size,
                              hipStream_t stream) {
  const float* x    = (const float*)d_in[0];
  const int*   ei   = (const int*)d_in[1];
  const int*   batch= (const int*)d_in[2];
  const float* W1   = (const float*)d_in[3];
  const float* a1s  = (const float*)d_in[4];
  const float* a1d  = (const float*)d_in[5];
  const float* b1   = (const float*)d_in[6];
  const float* W2   = (const float*)d_in[7];
  const float* a2s  = (const float*)d_in[8];
  const float* a2d  = (const float*)d_in[9];
  const float* b2   = (const float*)d_in[10];
  const float* W3   = (const float*)d_in[11];
  const float* a3s  = (const float*)d_in[12];
  const float* a3d  = (const float*)d_in[13];
  const float* b3   = (const float*)d_in[14];
  const float* Wp1  = (const float*)d_in[15];
  const float* bp1  = (const float*)d_in[16];
  const float* Wp2  = (const float*)d_in[17];
  const float* bp2  = (const float*)d_in[18];

  const int N = in_sizes[0] / 2;       // 100000
  const int E = in_sizes[1] / 2;       // 400000
  const int Et = E + N;                // with self loops

  char* base = (char*)d_ws;
  size_t off = 0;
  auto alloc = [&](size_t bytes) { size_t o = off; off = align_up(off + bytes, 256); return o; };
  u16*   h16    = (u16*)  (base + alloc((size_t)N * HC * 2));   // message-path h (bf16)
  u16*   xhi    = (u16*)  (base + alloc((size_t)N * HC * 2));   // gather out (bf16)
  float* als    = (float*)(base + alloc((size_t)N * 4 * 4));
  float* ald    = (float*)(base + alloc((size_t)N * 4 * 4));
  float* invS   = (float*)(base + alloc((size_t)N * 4 * 4));
  int*   rowptr = (int*)  (base + alloc((size_t)(N + 1) * 4));
  int*   col    = (int*)  (base + alloc((size_t)Et * 4));
  float* w      = (float*)(base + alloc((size_t)Et * 4 * 4));   // per-edge softmax numerators
  int*   deg    = (int*)  (base + alloc((size_t)N * 4));
  int*   cursor = (int*)  (base + alloc((size_t)N * 4));
  int*   bsum   = (int*)  (base + alloc(512 * 4));
  int*   bounds = (int*)  (base + alloc((GG + 1) * 4));
  float* pooled = (float*)(base + alloc((size_t)GG * HC * 4));
  (void)ws_size; (void)n_in; (void)out_size;

  // W2t/W3t hi/lo parked in deg/cursor space (dead after CSR build; 400 KB >= 256 KB)
  u16* W2thi = (u16*)deg;    u16* W2tlo = W2thi + 256 * 256;
  u16* W3thi = (u16*)cursor; u16* W3tlo = W3thi + 256 * 256;

  hipMemsetAsync(deg, 0, (size_t)N * 4, stream);
  hipMemsetAsync(cursor, 0, (size_t)N * 4, stream);
  hipMemsetAsync(pooled, 0, (size_t)GG * HC * 4, stream);

  // CSR by destination (same edge set for all layers)
  int ebk = (Et + 255) / 256;
  count_deg_kernel<<<ebk, 256, 0, stream>>>(ei, E, N, deg);
  int NT = (N + 255) / 256;
  scan_partial_kernel<<<NT, 256, 0, stream>>>(deg, N, rowptr, bsum);
  scan_bsum_kernel<<<1, 512, 0, stream>>>(bsum, NT);
  scan_add_kernel<<<NT, 256, 0, stream>>>(rowptr, bsum, N, Et);
  fill_csr_kernel<<<ebk, 256, 0, stream>>>(ei, E, N, rowptr, cursor, col);

  // weight conversion (deg/cursor now dead)
  convert_w_kernel<<<256, 256, 0, stream>>>(W2, W2thi, W2tlo);
  convert_w_kernel<<<256, 256, 0, stream>>>(W3, W3thi, W3tlo);

  dim3 gemm_grid(HC / GBN, (N + GBM - 1) / GBM);
  int nodeblk = (N + 3) / 4;

  // layer 1 (in=2, logits fused)
  gemm_k2_logits_kernel<<<nodeblk, 256, 0, stream>>>(x, W1, a1s, a1d, h16, als, ald, N);
  edge_softmax_kernel<<<NT, 256, 0, stream>>>(als, ald, rowptr, col, w, invS, N);
  gat_gather_kernel<<<nodeblk, 256, 0, stream>>>(h16, w, invS, rowptr, col, b1, xhi, N);
  // layer 2
  gemm_mfma_kernel<<<gemm_grid, 256, 0, stream>>>(xhi, W2thi, W2tlo, a2s, a2d,
                                                  h16, als, ald, N);
  edge_softmax_kernel<<<NT, 256, 0, stream>>>(als, ald, rowptr, col, w, invS, N);
  gat_gather_kernel<<<nodeblk, 256, 0, stream>>>(h16, w, invS, rowptr, col, b2, xhi, N);
  // layer 3
  gemm_mfma_kernel<<<gemm_grid, 256, 0, stream>>>(xhi, W3thi, W3tlo, a3s, a3d,
                                                  h16, als, ald, N);
  edge_softmax_kernel<<<NT, 256, 0, stream>>>(als, ald, rowptr, col, w, invS, N);
  gat_gather_kernel<<<nodeblk, 256, 0, stream>>>(h16, w, invS, rowptr, col, b3, xhi, N);

  // pool + MLP
  bounds_kernel<<<1, 128, 0, stream>>>(batch, N, bounds);
  pool_kernel<<<dim3(GG, 8), 256, 0, stream>>>(xhi, bounds, pooled);
  mlp_kernel<<<GG, 512, 0, stream>>>(pooled, bounds, Wp1, bp1, Wp2, bp2, (float*)d_out);
}